// Round 6
// baseline (268.924 us; speedup 1.0000x reference)
//
#include <hip/hip_runtime.h>
#include <hip/hip_bf16.h>
#include <math.h>

#define SEQ     512
#define BSZ     2
#define ROWS    (BSZ*SEQ)      // 1024
#define DMODEL  768
#define DINNER  1536
#define DSTATE  64
#define NHEADS  24
#define HEADDIM 64
#define CONVDIM 1664
#define DINPROJ 3224
#define DFF     3072
#define EPSF    1e-5f

typedef __attribute__((ext_vector_type(8))) short s16x8;   // 8 bf16 = 4 VGPRs
typedef __attribute__((ext_vector_type(4))) float f32x4;   // MFMA accumulator

__device__ __forceinline__ float b2f(const __hip_bfloat16 v){ return __bfloat162float(v); }
__device__ __forceinline__ __hip_bfloat16 f2b(float v){ return __float2bfloat16(v); }
__device__ __forceinline__ ushort f2bu(float v){
  union { __hip_bfloat16 b; ushort u; } c; c.b = __float2bfloat16(v); return c.u;
}
__device__ __forceinline__ float u2f(ushort u){ return __uint_as_float(((uint)u) << 16); }

// async global->LDS, 16B per lane; LDS dest = wave-uniform base + lane*16
__device__ __forceinline__ void gload16(const void* g, void* l){
  __builtin_amdgcn_global_load_lds((__attribute__((address_space(1))) const void*)g,
                                   (__attribute__((address_space(3))) void*)l, 16, 0, 0);
}

__device__ __forceinline__ float block_sum256(float v, float* sh){
  #pragma unroll
  for (int off = 32; off > 0; off >>= 1) v += __shfl_down(v, off, 64);
  int w = threadIdx.x >> 6;
  if ((threadIdx.x & 63) == 0) sh[w] = v;
  __syncthreads();
  float t = sh[0] + sh[1] + sh[2] + sh[3];
  __syncthreads();
  return t;
}

__global__ __launch_bounds__(256) void zerof_kernel(float* out, int n){
  int i = blockIdx.x*256 + threadIdx.x;
  if (i < n) out[i] = 0.f;
}

// ---- fused prep: [blocks < wblocks] all-weights fp32->bf16 ; [rest] ln1 ----
__global__ __launch_bounds__(256) void prep_kernel(const float* __restrict__ w0,
    const float* __restrict__ w1, const float* __restrict__ w2,
    const float* __restrict__ w3, ushort* __restrict__ o,
    int n0, int n1, int n2, int n3, int wblocks,
    const float* __restrict__ xin, const float* __restrict__ lnw,
    const float* __restrict__ lnb, __hip_bfloat16* __restrict__ xnout)
{
  __shared__ float sh[4];
  if ((int)blockIdx.x < wblocks){
    int i = (blockIdx.x*256 + threadIdx.x) << 2;
    int total = n0 + n1 + n2 + n3;
    if (i < total){
      const float* s; int off;
      if      (i < n0)       { s = w0; off = i; }
      else if (i < n0+n1)    { s = w1; off = i - n0; }
      else if (i < n0+n1+n2) { s = w2; off = i - n0 - n1; }
      else                   { s = w3; off = i - n0 - n1 - n2; }
      float4 f = *(const float4*)(s + off);
      *(ushort4*)(o + i) = make_ushort4(f2bu(f.x), f2bu(f.y), f2bu(f.z), f2bu(f.w));
    }
    return;
  }
  const int row = blockIdx.x - wblocks;
  const float* xr = xin + (size_t)row * DMODEL;
  float v[3]; float s = 0.f;
  #pragma unroll
  for (int i = 0; i < 3; i++){ int c = threadIdx.x + i*256; v[i] = xr[c]; s += v[i]; }
  s = block_sum256(s, sh);
  float mu = s * (1.f/DMODEL);
  float s2 = 0.f;
  #pragma unroll
  for (int i = 0; i < 3; i++){ float d = v[i]-mu; s2 += d*d; }
  s2 = block_sum256(s2, sh);
  float rs = rsqrtf(s2*(1.f/DMODEL) + EPSF);
  #pragma unroll
  for (int i = 0; i < 3; i++){
    int c = threadIdx.x + i*256;
    xnout[(size_t)row*DMODEL + c] = f2b((v[i]-mu)*rs*lnw[c] + lnb[c]);
  }
}

// ---- LayerNorm (fallback path) ----
__global__ __launch_bounds__(256) void ln_kernel(const float* __restrict__ in,
    const float* __restrict__ w, const float* __restrict__ b,
    __hip_bfloat16* __restrict__ out)
{
  __shared__ float sh[4];
  const int row = blockIdx.x;
  const float* xr = in + (size_t)row * DMODEL;
  float v[3]; float s = 0.f;
  #pragma unroll
  for (int i = 0; i < 3; i++){ int c = threadIdx.x + i*256; v[i] = xr[c]; s += v[i]; }
  s = block_sum256(s, sh);
  float mu = s * (1.f/DMODEL);
  float s2 = 0.f;
  #pragma unroll
  for (int i = 0; i < 3; i++){ float d = v[i]-mu; s2 += d*d; }
  s2 = block_sum256(s2, sh);
  float rs = rsqrtf(s2*(1.f/DMODEL) + EPSF);
  #pragma unroll
  for (int i = 0; i < 3; i++){
    int c = threadIdx.x + i*256;
    out[(size_t)row*DMODEL + c] = f2b((v[i]-mu)*rs*w[c] + b[c]);
  }
}

__device__ __forceinline__ s16x8 ld_frag(const ushort* p){
  union { ushort4 h[2]; s16x8 v; } u;
  u.h[0] = *(const ushort4*)(p);
  u.h[1] = *(const ushort4*)(p + 4);
  return u.v;
}

// ---- bf16 x bf16 MFMA GEMM, 64x64 tile, BK=64, gload_lds w16 ----
// 3-buffer pipeline, counted vmcnt(4) (= one 4-load stage in flight per wave),
// raw s_barrier. EPI: 0 = plain store, 1 = bias + exact GELU.
// KS>1: per-slice partial outputs C[z*M*N + ...] (no atomics).
template<typename CTy, int KS, int EPI>
__global__ __launch_bounds__(256) void gemm_bb64(const __hip_bfloat16* __restrict__ A_,
    const __hip_bfloat16* __restrict__ B_, CTy* __restrict__ C,
    const float* __restrict__ bias, int M, int N, int K)
{
  __shared__ __align__(16) ushort As[3][64][64];
  __shared__ __align__(16) ushort Bs[3][64][64];
  const int tid  = threadIdx.x;
  const int lane = tid & 63, wave = tid >> 6;
  const int wr = wave >> 1, wc = wave & 1;        // 2x2 wave grid
  const int n0 = blockIdx.x * 64, m0 = blockIdx.y * 64;
  const int Kc   = K / KS;
  const int kbeg = blockIdx.z * Kc;
  const int NT   = Kc >> 6;                        // K-tiles (>= 3 for all calls)
  const int srw  = lane >> 3;                      // row-in-issue 0..7
  const int scol = (((lane & 7) ^ srw) << 3);      // swizzled src chunk (ushorts)
  const int l15  = lane & 15;
  const int r7   = l15 & 7;                        // frag row & 7 (i*16 preserves)
  const int c0   = lane >> 4;                      // frag chunk base 0..3

  const ushort* Au = (const ushort*)A_;
  const ushort* Bu = (const ushort*)B_;

  f32x4 acc[2][2] = {};

  auto stage = [&](int bf, int k0){
    #pragma unroll
    for (int q = 0; q < 2; q++){
      int row = q*32 + wave*8 + srw;
      gload16(Au + (size_t)(m0 + row)*K + kbeg + k0 + scol, &As[bf][q*32 + wave*8][0]);
      int nr = n0 + row; if (nr > N-1) nr = N-1;   // clamp; garbage cols never stored
      gload16(Bu + (size_t)nr*K + kbeg + k0 + scol, &Bs[bf][q*32 + wave*8][0]);
    }
  };

  stage(0, 0);
  stage(1, 64);
  asm volatile("s_waitcnt vmcnt(4)" ::: "memory");   // tile 0 landed (all 4 loads)
  __builtin_amdgcn_s_barrier();

  for (int t = 0; t < NT; ++t){
    const int nxt = t + 2;
    if (nxt < NT) stage(nxt % 3, nxt << 6);          // keep 2 tiles in flight
    const int cur = t % 3;
    #pragma unroll
    for (int tt = 0; tt < 2; tt++){
      const int fc = (((tt*4 + c0) ^ r7) << 3);      // swizzled frag col (ushorts)
      s16x8 a0 = ld_frag(&As[cur][wr*32      + l15][fc]);
      s16x8 a1 = ld_frag(&As[cur][wr*32 + 16 + l15][fc]);
      s16x8 b0 = ld_frag(&Bs[cur][wc*32      + l15][fc]);
      s16x8 b1 = ld_frag(&Bs[cur][wc*32 + 16 + l15][fc]);
      acc[0][0] = __builtin_amdgcn_mfma_f32_16x16x32_bf16(a0, b0, acc[0][0], 0, 0, 0);
      acc[0][1] = __builtin_amdgcn_mfma_f32_16x16x32_bf16(a0, b1, acc[0][1], 0, 0, 0);
      acc[1][0] = __builtin_amdgcn_mfma_f32_16x16x32_bf16(a1, b0, acc[1][0], 0, 0, 0);
      acc[1][1] = __builtin_amdgcn_mfma_f32_16x16x32_bf16(a1, b1, acc[1][1], 0, 0, 0);
    }
    if (t == NT-1) break;                            // no further reads
    if (nxt < NT) { asm volatile("s_waitcnt vmcnt(4)" ::: "memory"); }
    else          { asm volatile("s_waitcnt vmcnt(0)" ::: "memory"); }
    __builtin_amdgcn_s_barrier();
  }

  CTy* Cz = C + (size_t)blockIdx.z * M * N;
  // C/D layout (verified m89/m91): col = lane&15, row = (lane>>4)*4 + reg
  const int crow = (lane >> 4) * 4;
  #pragma unroll
  for (int i = 0; i < 2; i++){
    #pragma unroll
    for (int j = 0; j < 2; j++){
      int col = n0 + wc*32 + j*16 + l15;
      if (col < N){
        #pragma unroll
        for (int q = 0; q < 4; q++){
          int rowg = m0 + wr*32 + i*16 + crow + q;
          if constexpr (EPI == 1){
            float v = acc[i][j][q] + bias[col];
            Cz[(size_t)rowg*N + col] = (CTy)f2b(0.5f * v * (1.f + erff(v * 0.70710678118654752f)));
          } else if constexpr (sizeof(CTy) == 4){
            Cz[(size_t)rowg*N + col] = acc[i][j][q];
          } else {
            Cz[(size_t)rowg*N + col] = (CTy)f2b(acc[i][j][q]);
          }
        }
      }
    }
  }
}

// ---- fallback MFMA GEMM (fp32 B, 64x64 tile) -- used only if ws too small ----
template<typename CTy>
__global__ __launch_bounds__(256) void gemm_mfma(const __hip_bfloat16* __restrict__ A,
    const float* __restrict__ B, CTy* __restrict__ C, int M, int N, int K)
{
  __shared__ __align__(16) ushort As[64][72];
  __shared__ __align__(16) ushort Bs[64][72];
  const int tid  = threadIdx.x;
  const int lane = tid & 63, wave = tid >> 6;
  const int wr = wave >> 1, wc = wave & 1;
  const int n0 = blockIdx.x * 64, m0 = blockIdx.y * 64;
  const int sr = tid >> 2;
  const int sc = (tid & 3) * 16;
  const int l15 = lane & 15, lk = (lane >> 4) * 8;

  f32x4 acc[2][2] = {};

  const ushort* Au = (const ushort*)A;
  int nr = n0 + sr; if (nr > N-1) nr = N-1;

  for (int k0 = 0; k0 < K; k0 += 64){
    const ushort* ag = Au + (size_t)(m0 + sr)*K + (k0 + sc);
    ushort4 a0 = *(const ushort4*)(ag);
    ushort4 a1 = *(const ushort4*)(ag + 4);
    ushort4 a2 = *(const ushort4*)(ag + 8);
    ushort4 a3 = *(const ushort4*)(ag + 12);
    const float* bg = B + (size_t)nr*K + (k0 + sc);
    float4 f0 = *(const float4*)(bg);
    float4 f1 = *(const float4*)(bg + 4);
    float4 f2 = *(const float4*)(bg + 8);
    float4 f3 = *(const float4*)(bg + 12);
    ushort4 b0 = make_ushort4(f2bu(f0.x), f2bu(f0.y), f2bu(f0.z), f2bu(f0.w));
    ushort4 b1 = make_ushort4(f2bu(f1.x), f2bu(f1.y), f2bu(f1.z), f2bu(f1.w));
    ushort4 b2 = make_ushort4(f2bu(f2.x), f2bu(f2.y), f2bu(f2.z), f2bu(f2.w));
    ushort4 b3 = make_ushort4(f2bu(f3.x), f2bu(f3.y), f2bu(f3.z), f2bu(f3.w));

    __syncthreads();
    *(ushort4*)&As[sr][sc +  0] = a0;
    *(ushort4*)&As[sr][sc +  4] = a1;
    *(ushort4*)&As[sr][sc +  8] = a2;
    *(ushort4*)&As[sr][sc + 12] = a3;
    *(ushort4*)&Bs[sr][sc +  0] = b0;
    *(ushort4*)&Bs[sr][sc +  4] = b1;
    *(ushort4*)&Bs[sr][sc +  8] = b2;
    *(ushort4*)&Bs[sr][sc + 12] = b3;
    __syncthreads();

    #pragma unroll
    for (int kk = 0; kk < 64; kk += 32){
      s16x8 af0 = ld_frag(&As[wr*32      + l15][kk + lk]);
      s16x8 af1 = ld_frag(&As[wr*32 + 16 + l15][kk + lk]);
      s16x8 bf0 = ld_frag(&Bs[wc*32      + l15][kk + lk]);
      s16x8 bf1 = ld_frag(&Bs[wc*32 + 16 + l15][kk + lk]);
      acc[0][0] = __builtin_amdgcn_mfma_f32_16x16x32_bf16(af0, bf0, acc[0][0], 0, 0, 0);
      acc[0][1] = __builtin_amdgcn_mfma_f32_16x16x32_bf16(af0, bf1, acc[0][1], 0, 0, 0);
      acc[1][0] = __builtin_amdgcn_mfma_f32_16x16x32_bf16(af1, bf0, acc[1][0], 0, 0, 0);
      acc[1][1] = __builtin_amdgcn_mfma_f32_16x16x32_bf16(af1, bf1, acc[1][1], 0, 0, 0);
    }
  }

  const int crow = (lane >> 4) * 4;
  #pragma unroll
  for (int i = 0; i < 2; i++){
    #pragma unroll
    for (int j = 0; j < 2; j++){
      int col = n0 + wc*32 + j*16 + l15;
      if (col < N){
        #pragma unroll
        for (int q = 0; q < 4; q++){
          int rowg = m0 + wr*32 + i*16 + crow + q;
          if constexpr (sizeof(CTy) == 4) C[(size_t)rowg*N + col] = acc[i][j][q];
          else                            C[(size_t)rowg*N + col] = (CTy)f2b(acc[i][j][q]);
        }
      }
    }
  }
}

// ---- causal depthwise conv(4) + bias + silu (both dirs) + dt/dA prep ----
__global__ __launch_bounds__(256) void convdt_kernel(const __hip_bfloat16* __restrict__ zx,
    const float* __restrict__ cw, const float* __restrict__ cb,
    const float* __restrict__ dt_bias, const float* __restrict__ A_log,
    __hip_bfloat16* __restrict__ xconv, float* __restrict__ dtb, float* __restrict__ dab)
{
  const int tt = blockIdx.x, b = blockIdx.y, dir = blockIdx.z;
  const int c8 = threadIdx.x * 8;
  if (c8 < CONVDIM){
    size_t rowoff[4]; bool ok[4];
    #pragma unroll
    for (int k = 0; k < 4; k++){
      int s = tt - 3 + k;
      ok[k] = (s >= 0);
      int ss = ok[k] ? s : 0;
      int phys = dir ? (SEQ-1-ss) : ss;
      rowoff[k] = ((size_t)(b*SEQ + phys))*DINPROJ + DINNER + c8;
    }
    float acc[8];
    {
      float4 cb0 = *(const float4*)(cb + c8);
      float4 cb1 = *(const float4*)(cb + c8 + 4);
      acc[0]=cb0.x; acc[1]=cb0.y; acc[2]=cb0.z; acc[3]=cb0.w;
      acc[4]=cb1.x; acc[5]=cb1.y; acc[6]=cb1.z; acc[7]=cb1.w;
    }
    float wv[8][4];
    #pragma unroll
    for (int j = 0; j < 8; j++){
      float4 w4 = *(const float4*)(cw + (size_t)(c8 + j)*4);
      wv[j][0]=w4.x; wv[j][1]=w4.y; wv[j][2]=w4.z; wv[j][3]=w4.w;
    }
    const ushort* zu = (const ushort*)zx;
    #pragma unroll
    for (int k = 0; k < 4; k++){
      if (ok[k]){
        ushort4 v0 = *(const ushort4*)(zu + rowoff[k]);
        ushort4 v1 = *(const ushort4*)(zu + rowoff[k] + 4);
        acc[0] = fmaf(wv[0][k], u2f(v0.x), acc[0]);
        acc[1] = fmaf(wv[1][k], u2f(v0.y), acc[1]);
        acc[2] = fmaf(wv[2][k], u2f(v0.z), acc[2]);
        acc[3] = fmaf(wv[3][k], u2f(v0.w), acc[3]);
        acc[4] = fmaf(wv[4][k], u2f(v1.x), acc[4]);
        acc[5] = fmaf(wv[5][k], u2f(v1.y), acc[5]);
        acc[6] = fmaf(wv[6][k], u2f(v1.z), acc[6]);
        acc[7] = fmaf(wv[7][k], u2f(v1.w), acc[7]);
      }
    }
    ushort* outr = (ushort*)xconv + ((size_t)((dir*BSZ + b)*SEQ + tt))*CONVDIM + c8;
    ushort o[8];
    #pragma unroll
    for (int j = 0; j < 8; j++){
      float s = acc[j] / (1.f + expf(-acc[j]));   // silu
      o[j] = f2bu(s);
    }
    *(ushort4*)(outr)     = make_ushort4(o[0],o[1],o[2],o[3]);
    *(ushort4*)(outr + 4) = make_ushort4(o[4],o[5],o[6],o[7]);
  }
  if (dir == 0 && threadIdx.x < NHEADS){
    int h = threadIdx.x;
    size_t r = (size_t)b*SEQ + tt;
    float raw = b2f(zx[r*DINPROJ + (DINNER + CONVDIM) + h]) + dt_bias[h];
    float sp  = fmaxf(raw, 0.f) + log1pf(expf(-fabsf(raw)));   // stable softplus
    dtb[r*NHEADS + h] = sp;
    dab[r*NHEADS + h] = expf(-sp * expf(A_log[h]));
  }
}

// ======================= chunked selective scan =======================
#define CT 16

// pass1: local chunk scan, state update only. grid (NC-1, NHEADS, 4)
__global__ __launch_bounds__(256) void scan_pass1(const __hip_bfloat16* __restrict__ xconv,
    const float* __restrict__ dtb, const float* __restrict__ dab,
    float* __restrict__ stateBuf, int CL)
{
  const int c = blockIdx.x, h = blockIdx.y, z = blockIdx.z;
  const int b = z & 1, dir = z >> 1;
  const int tid = threadIdx.x, lane = tid & 63, wave = tid >> 6, nb = wave * 16;
  __shared__ __align__(16) float Bc[CT][64], Xc[CT][64];
  __shared__ float dAc[CT], dtc[CT];
  float hreg[16];
  #pragma unroll
  for (int j = 0; j < 16; j++) hreg[j] = 0.f;
  const size_t dirbase = (size_t)z * SEQ;
  const int cstart = c * CL;

  const int ttl = tid >> 4, c4 = (tid & 15) << 2;

  for (int c0 = cstart; c0 < cstart + CL; c0 += CT){
    {
      const ushort* rowp = (const ushort*)xconv + (dirbase + c0 + ttl)*(size_t)CONVDIM;
      ushort4 bv = *(const ushort4*)(rowp + DINNER + c4);
      ushort4 xv = *(const ushort4*)(rowp + h*HEADDIM + c4);
      Bc[ttl][c4+0] = u2f(bv.x); Bc[ttl][c4+1] = u2f(bv.y);
      Bc[ttl][c4+2] = u2f(bv.z); Bc[ttl][c4+3] = u2f(bv.w);
      Xc[ttl][c4+0] = u2f(xv.x); Xc[ttl][c4+1] = u2f(xv.y);
      Xc[ttl][c4+2] = u2f(xv.z); Xc[ttl][c4+3] = u2f(xv.w);
    }
    if (tid < CT){
      int phys = dir ? (SEQ-1 - (c0 + tid)) : (c0 + tid);
      size_t r = (size_t)b*SEQ + phys;
      dAc[tid] = dab[r*NHEADS + h];
      dtc[tid] = dtb[r*NHEADS + h];
    }
    __syncthreads();

    #pragma unroll 4
    for (int tt = 0; tt < CT; tt++){
      float dA = dAc[tt];
      float dtx = dtc[tt] * Xc[tt][lane];
      const float4* Bq = (const float4*)&Bc[tt][nb];
      float4 B0 = Bq[0], B1 = Bq[1], B2 = Bq[2], B3 = Bq[3];
      hreg[ 0]=fmaf(dA,hreg[ 0],dtx*B0.x); hreg[ 1]=fmaf(dA,hreg[ 1],dtx*B0.y);
      hreg[ 2]=fmaf(dA,hreg[ 2],dtx*B0.z); hreg[ 3]=fmaf(dA,hreg[ 3],dtx*B0.w);
      hreg[ 4]=fmaf(dA,hreg[ 4],dtx*B1.x); hreg[ 5]=fmaf(dA,hreg[ 5],dtx*B1.y);
      hreg[ 6]=fmaf(dA,hreg[ 6],dtx*B1.z); hreg[ 7]=fmaf(dA,hreg[ 7],dtx*B1.w);
      hreg[ 8]=fmaf(dA,hreg[ 8],dtx*B2.x); hreg[ 9]=fmaf(dA,hreg[ 9],dtx*B2.y);
      hreg[10]=fmaf(dA,hreg[10],dtx*B2.z); hreg[11]=fmaf(dA,hreg[11],dtx*B2.w);
      hreg[12]=fmaf(dA,hreg[12],dtx*B3.x); hreg[13]=fmaf(dA,hreg[13],dtx*B3.y);
      hreg[14]=fmaf(dA,hreg[14],dtx*B3.z); hreg[15]=fmaf(dA,hreg[15],dtx*B3.w);
    }
    __syncthreads();
  }

  float* sp = stateBuf + (((size_t)c*4 + z)*NHEADS + h)*4096 + (size_t)lane*64 + nb;
  *(float4*)(sp +  0) = make_float4(hreg[ 0],hreg[ 1],hreg[ 2],hreg[ 3]);
  *(float4*)(sp +  4) = make_float4(hreg[ 4],hreg[ 5],hreg[ 6],hreg[ 7]);
  *(float4*)(sp +  8) = make_float4(hreg[ 8],hreg[ 9],hreg[10],hreg[11]);
  *(float4*)(sp + 12) = make_float4(hreg[12],hreg[13],hreg[14],hreg[15]);
}

// pass2: full scan per chunk; h_init reconstructed in-block from L-states
// (fixup fused: h_init[c] = sum_{i<c} (prod_{j=i+1..c-1} P_j) L_i).
// grid (NC, NHEADS, 4)
__global__ __launch_bounds__(256) void scan_pass2(const __hip_bfloat16* __restrict__ xconv,
    const __hip_bfloat16* __restrict__ zx, const float* __restrict__ dtb,
    const float* __restrict__ dab, const float* __restrict__ Dp,
    const float* __restrict__ stateBuf, __hip_bfloat16* __restrict__ yg, int CL)
{
  const int c = blockIdx.x, h = blockIdx.y, z = blockIdx.z;
  const int b = z & 1, dir = z >> 1;
  const int tid = threadIdx.x, lane = tid & 63, wave = tid >> 6, nb = wave * 16;
  __shared__ __align__(16) float Bc[CT][64], Cc[CT][64], Xc[CT][64];
  __shared__ __align__(16) float Yp[4][CT][64];
  __shared__ float dAc[CT], dtc[CT];
  __shared__ float sP[8];
  float hreg[16];
  #pragma unroll
  for (int j = 0; j < 16; j++) hreg[j] = 0.f;
  if (c > 0){
    // chunk dA-products P_j for j < c
    if (tid < c){
      float p = 1.f;
      for (int i = 0; i < CL; i++){
        int t = tid*CL + i;
        int phys = dir ? (SEQ-1 - t) : t;
        p *= dab[((size_t)b*SEQ + phys)*NHEADS + h];
      }
      sP[tid] = p;
    }
    __syncthreads();
    float suffix = 1.f;
    for (int i = c-1; i >= 0; --i){
      const float* sp = stateBuf + (((size_t)i*4 + z)*NHEADS + h)*4096 + (size_t)lane*64 + nb;
      float4 s0 = *(const float4*)(sp+0), s1 = *(const float4*)(sp+4);
      float4 s2 = *(const float4*)(sp+8), s3 = *(const float4*)(sp+12);
      hreg[ 0]=fmaf(suffix,s0.x,hreg[ 0]); hreg[ 1]=fmaf(suffix,s0.y,hreg[ 1]);
      hreg[ 2]=fmaf(suffix,s0.z,hreg[ 2]); hreg[ 3]=fmaf(suffix,s0.w,hreg[ 3]);
      hreg[ 4]=fmaf(suffix,s1.x,hreg[ 4]); hreg[ 5]=fmaf(suffix,s1.y,hreg[ 5]);
      hreg[ 6]=fmaf(suffix,s1.z,hreg[ 6]); hreg[ 7]=fmaf(suffix,s1.w,hreg[ 7]);
      hreg[ 8]=fmaf(suffix,s2.x,hreg[ 8]); hreg[ 9]=fmaf(suffix,s2.y,hreg[ 9]);
      hreg[10]=fmaf(suffix,s2.z,hreg[10]); hreg[11]=fmaf(suffix,s2.w,hreg[11]);
      hreg[12]=fmaf(suffix,s3.x,hreg[12]); hreg[13]=fmaf(suffix,s3.y,hreg[13]);
      hreg[14]=fmaf(suffix,s3.z,hreg[14]); hreg[15]=fmaf(suffix,s3.w,hreg[15]);
      suffix *= sP[i];
    }
    __syncthreads();
  }
  const float Dh = Dp[h];
  const size_t dirbase = (size_t)z * SEQ;
  const int cstart = c * CL;
  const int ttl = tid >> 4, c4 = (tid & 15) << 2;

  for (int c0 = cstart; c0 < cstart + CL; c0 += CT){
    {
      const ushort* rowp = (const ushort*)xconv + (dirbase + c0 + ttl)*(size_t)CONVDIM;
      ushort4 bv = *(const ushort4*)(rowp + DINNER + c4);
      ushort4 cv = *(const ushort4*)(rowp + DINNER + DSTATE + c4);
      ushort4 xv = *(const ushort4*)(rowp + h*HEADDIM + c4);
      Bc[ttl][c4+0] = u2f(bv.x); Bc[ttl][c4+1] = u2f(bv.y);
      Bc[ttl][c4+2] = u2f(bv.z); Bc[ttl][c4+3] = u2f(bv.w);
      Cc[ttl][c4+0] = u2f(cv.x); Cc[ttl][c4+1] = u2f(cv.y);
      Cc[ttl][c4+2] = u2f(cv.z); Cc[ttl][c4+3] = u2f(cv.w);
      Xc[ttl][c4+0] = u2f(xv.x); Xc[ttl][c4+1] = u2f(xv.y);
      Xc[ttl][c4+2] = u2f(xv.z); Xc[ttl][c4+3] = u2f(xv.w);
    }
    if (tid < CT){
      int phys = dir ? (SEQ-1 - (c0 + tid)) : (c0 + tid);
      size_t r = (size_t)b*SEQ + phys;
      dAc[tid] = dab[r*NHEADS + h];
      dtc[tid] = dtb[r*NHEADS + h];
    }
    __syncthreads();

    #pragma unroll 4
    for (int tt = 0; tt < CT; tt++){
      float dA = dAc[tt];
      float dtx = dtc[tt] * Xc[tt][lane];
      const float4* Bq = (const float4*)&Bc[tt][nb];
      const float4* Cq = (const float4*)&Cc[tt][nb];
      float4 B0 = Bq[0], B1 = Bq[1], B2 = Bq[2], B3 = Bq[3];
      float4 C0 = Cq[0], C1 = Cq[1], C2 = Cq[2], C3 = Cq[3];
      float y0 = 0.f, y1 = 0.f, y2 = 0.f, y3 = 0.f;
      hreg[ 0]=fmaf(dA,hreg[ 0],dtx*B0.x); y0=fmaf(hreg[ 0],C0.x,y0);
      hreg[ 1]=fmaf(dA,hreg[ 1],dtx*B0.y); y1=fmaf(hreg[ 1],C0.y,y1);
      hreg[ 2]=fmaf(dA,hreg[ 2],dtx*B0.z); y2=fmaf(hreg[ 2],C0.z,y2);
      hreg[ 3]=fmaf(dA,hreg[ 3],dtx*B0.w); y3=fmaf(hreg[ 3],C0.w,y3);
      hreg[ 4]=fmaf(dA,hreg[ 4],dtx*B1.x); y0=fmaf(hreg[ 4],C1.x,y0);
      hreg[ 5]=fmaf(dA,hreg[ 5],dtx*B1.y); y1=fmaf(hreg[ 5],C1.y,y1);
      hreg[ 6]=fmaf(dA,hreg[ 6],dtx*B1.z); y2=fmaf(hreg[ 6],C1.z,y2);
      hreg[ 7]=fmaf(dA,hreg[ 7],dtx*B1.w); y3=fmaf(hreg[ 7],C1.w,y3);
      hreg[ 8]=fmaf(dA,hreg[ 8],dtx*B2.x); y0=fmaf(hreg[ 8],C2.x,y0);
      hreg[ 9]=fmaf(dA,hreg[ 9],dtx*B2.y); y1=fmaf(hreg[ 9],C2.y,y1);
      hreg[10]=fmaf(dA,hreg[10],dtx*B2.z); y2=fmaf(hreg[10],C2.z,y2);
      hreg[11]=fmaf(dA,hreg[11],dtx*B2.w); y3=fmaf(hreg[11],C2.w,y3);
      hreg[12]=fmaf(dA,hreg[12],dtx*B3.x); y0=fmaf(hreg[12],C3.x,y0);
      hreg[13]=fmaf(dA,hreg[13],dtx*B3.y); y1=fmaf(hreg[13],C3.y,y1);
      hreg[14]=fmaf(dA,hreg[14],dtx*B3.z); y2=fmaf(hreg[14],C3.z,y2);
      hreg[15]=fmaf(dA,hreg[15],dtx*B3.w); y3=fmaf(hreg[15],C3.w,y3);
      Yp[wave][tt][lane] = (y0+y1) + (y2+y3);
    }
    __syncthreads();

    {
      // vectorized epilogue: 4 consecutive p per thread
      int tl = tid >> 4, p4 = (tid & 15) << 2;
      float4 ya = *(const float4*)&Yp[0][tl][p4];
      float4 yb4 = *(const float4*)&Yp[1][tl][p4];
      float4 yc = *(const float4*)&Yp[2][tl][p4];
      float4 yd = *(const float4*)&Yp[3][tl][p4];
      float4 xv = *(const float4*)&Xc[tl][p4];
      int phys = dir ? (SEQ-1 - (c0 + tl)) : (c0 + tl);
      size_t r = (size_t)b*SEQ + phys;
      const ushort* zp = (const ushort*)zx + r*DINPROJ + h*HEADDIM + p4;
      ushort4 zv = *(const ushort4*)zp;
      float zf[4] = { u2f(zv.x), u2f(zv.y), u2f(zv.z), u2f(zv.w) };
      float yv[4] = { ya.x+yb4.x+yc.x+yd.x + Dh*xv.x,
                      ya.y+yb4.y+yc.y+yd.y + Dh*xv.y,
                      ya.z+yb4.z+yc.z+yd.z + Dh*xv.z,
                      ya.w+yb4.w+yc.w+yd.w + Dh*xv.w };
      ushort o[4];
      #pragma unroll
      for (int j = 0; j < 4; j++){
        float sil = zf[j] / (1.f + expf(-zf[j]));
        o[j] = f2bu(yv[j] * sil);
      }
      ushort* op = (ushort*)yg + ((size_t)dir*ROWS + r)*DINNER + h*HEADDIM + p4;
      *(ushort4*)op = make_ushort4(o[0],o[1],o[2],o[3]);
    }
    __syncthreads();
  }
}

// ---- per-row gated RMSNorm both dirs + combine (fp32 norm_w) -> u bf16 ----
__global__ __launch_bounds__(256) void rmscomb_kernel(const __hip_bfloat16* __restrict__ yg,
    const float* __restrict__ nw, __hip_bfloat16* __restrict__ u)
{
  __shared__ float sh[4];
  const int row = blockIdx.x;
  const __hip_bfloat16* yf = yg + (size_t)row*DINNER;
  const __hip_bfloat16* yb = yg + (size_t)(ROWS + row)*DINNER;
  float vf[6], vb[6]; float sf = 0.f, sb = 0.f;
  #pragma unroll
  for (int i = 0; i < 6; i++){
    int c = threadIdx.x + i*256;
    vf[i] = b2f(yf[c]); sf += vf[i]*vf[i];
    vb[i] = b2f(yb[c]); sb += vb[i]*vb[i];
  }
  sf = block_sum256(sf, sh);
  sb = block_sum256(sb, sh);
  float rf = rsqrtf(sf*(1.f/DINNER) + EPSF);
  float rb = rsqrtf(sb*(1.f/DINNER) + EPSF);
  #pragma unroll
  for (int i = 0; i < 6; i++){
    int c = threadIdx.x + i*256;
    u[(size_t)row*DINNER + c] = f2b((vf[i]*rf + vb[i]*rb) * nw[c]);
  }
}

// ---- ln2 on NP fp32 partials -> bf16 mb ----
template<int NP>
__global__ __launch_bounds__(256) void ln2_kernel(const float* __restrict__ in,
    size_t pstride, const float* __restrict__ w, const float* __restrict__ b,
    __hip_bfloat16* __restrict__ out)
{
  __shared__ float sh[4];
  const int row = blockIdx.x;
  float v[3]; float s = 0.f;
  #pragma unroll
  for (int i = 0; i < 3; i++){
    int c = threadIdx.x + i*256;
    size_t idx = (size_t)row*DMODEL + c;
    float t = 0.f;
    #pragma unroll
    for (int p = 0; p < NP; p++) t += in[p*pstride + idx];
    v[i] = t; s += t;
  }
  s = block_sum256(s, sh);
  float mu = s * (1.f/DMODEL);
  float s2 = 0.f;
  #pragma unroll
  for (int i = 0; i < 3; i++){ float d = v[i]-mu; s2 += d*d; }
  s2 = block_sum256(s2, sh);
  float rs = rsqrtf(s2*(1.f/DMODEL) + EPSF);
  #pragma unroll
  for (int i = 0; i < 3; i++){
    int c = threadIdx.x + i*256;
    out[(size_t)row*DMODEL + c] = f2b((v[i]-mu)*rs*w[c] + b[c]);
  }
}

// ---- exact GELU with fp32 bias (fallback path only) ----
__global__ __launch_bounds__(256) void gelu_kernel(const __hip_bfloat16* __restrict__ g,
    const float* __restrict__ b1, __hip_bfloat16* __restrict__ out)
{
  size_t idx = (size_t)blockIdx.x*256 + threadIdx.x;
  int c = (int)(idx % DFF);
  float v = b2f(g[idx]) + b1[c];
  out[idx] = f2b(0.5f * v * (1.f + erff(v * 0.70710678118654752f)));
}

// ---- final: sum NP fp32 partials + bias + residual -> fp32 out (x4 vec) ----
template<int NP>
__global__ __launch_bounds__(256) void final_kernel(const float* __restrict__ f,
    size_t pstride, const float* __restrict__ bias, const float* __restrict__ x,
    float* __restrict__ out)
{
  size_t i4 = ((size_t)blockIdx.x*256 + threadIdx.x) << 2;
  int c = (int)(i4 % DMODEL);
  float4 bv = *(const float4*)(bias + c);
  float4 xv = *(const float4*)(x + i4);
  float4 s = make_float4(bv.x+xv.x, bv.y+xv.y, bv.z+xv.z, bv.w+xv.w);
  #pragma unroll
  for (int p = 0; p < NP; p++){
    float4 fv = *(const float4*)(f + p*pstride + i4);
    s.x += fv.x; s.y += fv.y; s.z += fv.z; s.w += fv.w;
  }
  *(float4*)(out + i4) = s;
}

extern "C" void kernel_launch(void* const* d_in, const int* in_sizes, int n_in,
                              void* d_out, int out_size, void* d_ws, size_t ws_size,
                              hipStream_t stream)
{
  float* out = (float*)d_out;

  const size_t NEED = 19906560;   // base plan (proven to fit)
  if (ws_size < NEED || n_in < 17){
    zerof_kernel<<<(out_size + 255)/256, 256, 0, stream>>>(out, out_size);
    return;
  }

  const float* x       = (const float*)d_in[0];
  const float* in_proj_w = (const float*)d_in[1];
  const float* conv_w  = (const float*)d_in[2];
  const float* conv_b  = (const float*)d_in[3];
  const float* dt_bias = (const float*)d_in[4];
  const float* A_log   = (const float*)d_in[5];
  const float* D_param = (const float*)d_in[6];
  const float* norm_w  = (const float*)d_in[7];
  const float* out_proj_w = (const float*)d_in[8];
  const float* ln1_w   = (const float*)d_in[9];
  const float* ln1_b   = (const float*)d_in[10];
  const float* ln2_w   = (const float*)d_in[11];
  const float* ln2_b   = (const float*)d_in[12];
  const float* ff_w1   = (const float*)d_in[13];
  const float* ff_b1   = (const float*)d_in[14];
  const float* ff_w2   = (const float*)d_in[15];
  const float* ff_b2   = (const float*)d_in[16];

  char* ws = (char*)d_ws;
  __hip_bfloat16* zx  = (__hip_bfloat16*)(ws + 0);         // 6,602,752
  __hip_bfloat16* xn  = (__hip_bfloat16*)(ws + 6602752);   // 1,572,864 (dead after s2)
  float*          dtb = (float*)(ws + 6602752);            //    98,304 (over xn)
  float*          dab = (float*)(ws + 6701056);            //    98,304
  __hip_bfloat16* xcv = (__hip_bfloat16*)(ws + 6799360);   // 6,815,744 -> 13,615,104
  __hip_bfloat16* yg  = (__hip_bfloat16*)(ws + 13615104);  // 6,291,456 -> 19,906,560
  __hip_bfloat16* u   = (__hip_bfloat16*)(ws + 0);         // over zx (dead after scan)
  float*          mo  = (float*)(ws + 3145728);            // over zx (fallback)
  __hip_bfloat16* mb  = (__hip_bfloat16*)(ws + 0);         // over u (dead)
  __hip_bfloat16* g   = (__hip_bfloat16*)(ws + 6799360);   // over xcv (fallback)
  __hip_bfloat16* gb  = (__hip_bfloat16*)(ws + 13615104);  // over yg (dead)
  float*          fo  = (float*)(ws + 0);                  // over mb (fallback)

  // fast-path extra regions beyond base plan (ws observed ~268 MB):
  const size_t WBALL = 16748544;        // all 4 weight matrices bf16
  const size_t PARTS = 12582912;        // 4 fp32 partials of ROWS*DMODEL
  const size_t CHB   = 1572864;         // per-chunk scan states
  const size_t PSTRIDE = (size_t)ROWS * DMODEL;
  const int WN_IN  = DINPROJ*DMODEL;    // 2,476,032
  const int WN_OUT = DMODEL*DINNER;     // 1,179,648
  const int WN_F1  = DFF*DMODEL;        // 2,359,296
  const int WN_F2  = DMODEL*DFF;        // 2,359,296

  size_t rem = ws_size - NEED;
  bool fast = (rem >= WBALL + PARTS);
  ushort* wb    = (ushort*)(ws + NEED);
  float*  parts = (float*) (ws + NEED + WBALL);
  size_t scanoff = NEED + (fast ? (WBALL + PARTS) : 0);
  size_t srem = ws_size - scanoff;
  int NC = 1;
  if      (srem >= 8*CHB) NC = 8;
  else if (srem >= 4*CHB) NC = 4;
  else if (srem >= 2*CHB) NC = 2;
  float* stateBuf = (float*)(ws + scanoff);
  const int CL = SEQ / NC;

  if (fast){
    // 1+2) fused: weight conversion (all 4) + ln1
    const int wblocks = (WN_IN + WN_OUT + WN_F1 + WN_F2) / 4 / 256;   // 8178 exact
    prep_kernel<<<wblocks + ROWS, 256, 0, stream>>>(in_proj_w, out_proj_w, ff_w1, ff_w2,
        wb, WN_IN, WN_OUT, WN_F1, WN_F2, wblocks, x, ln1_w, ln1_b, xn);
    // 3) in_proj -> zx bf16
    gemm_bb64<__hip_bfloat16,1,0><<<dim3((DINPROJ+63)/64, ROWS/64), 256, 0, stream>>>(
        xn, (const __hip_bfloat16*)wb, zx, nullptr, ROWS, DINPROJ, DMODEL);
  } else {
    ln_kernel<<<ROWS, 256, 0, stream>>>(x, ln1_w, ln1_b, xn);
    gemm_mfma<<<dim3((DINPROJ+63)/64, ROWS/64), 256, 0, stream>>>(xn, in_proj_w, zx, ROWS, DINPROJ, DMODEL);
  }
  // 4) conv + silu + dt/dA
  convdt_kernel<<<dim3(SEQ, BSZ, 2), 256, 0, stream>>>(zx, conv_w, conv_b, dt_bias, A_log, xcv, dtb, dab);
  // 5) chunked scan (pass2 reconstructs h_init; no fixup kernel)
  if (NC > 1){
    scan_pass1<<<dim3(NC-1, NHEADS, 4), 256, 0, stream>>>(xcv, dtb, dab, stateBuf, CL);
  }
  scan_pass2<<<dim3(NC, NHEADS, 4), 256, 0, stream>>>(xcv, zx, dtb, dab, D_param, stateBuf, yg, CL);
  // 6) per-dir RMS + combine -> u
  rmscomb_kernel<<<ROWS, 256, 0, stream>>>(yg, norm_w, u);
  // 7) out_proj [split-K=2, partials] ; 8) ln2 sums partials
  if (fast){
    gemm_bb64<float,2,0><<<dim3(DMODEL/64, ROWS/64, 2), 256, 0, stream>>>(
        u, (const __hip_bfloat16*)(wb + WN_IN), parts, nullptr, ROWS, DMODEL, DINNER);
    ln2_kernel<2><<<ROWS, 256, 0, stream>>>(parts, PSTRIDE, ln2_w, ln2_b, mb);
  } else {
    gemm_mfma<<<dim3(DMODEL/64, ROWS/64), 256, 0, stream>>>(u, out_proj_w, mo, ROWS, DMODEL, DINNER);
    ln2_kernel<1><<<ROWS, 256, 0, stream>>>(mo, 0, ln2_w, ln2_b, mb);
  }
  // 9) ff1 (+bias+gelu fused) -> gb
  if (fast){
    gemm_bb64<__hip_bfloat16,1,1><<<dim3(DFF/64, ROWS/64), 256, 0, stream>>>(
        mb, (const __hip_bfloat16*)(wb + WN_IN + WN_OUT), gb, ff_b1, ROWS, DFF, DMODEL);
  } else {
    gemm_mfma<<<dim3(DFF/64, ROWS/64), 256, 0, stream>>>(mb, ff_w1, g, ROWS, DFF, DMODEL);
    gelu_kernel<<<(ROWS*DFF)/256, 256, 0, stream>>>(g, ff_b1, gb);
  }
  // 10) ff2 [split-K=4, partials] ; 11) final sums + bias + residual
  if (fast){
    gemm_bb64<float,4,0><<<dim3(DMODEL/64, ROWS/64, 4), 256, 0, stream>>>(
        gb, (const __hip_bfloat16*)(wb + WN_IN + WN_OUT + WN_F1), parts, nullptr, ROWS, DMODEL, DFF);
    final_kernel<4><<<(ROWS*DMODEL/4)/256, 256, 0, stream>>>(parts, PSTRIDE, ff_b2, x, out);
  } else {
    gemm_mfma<<<dim3(DMODEL/64, ROWS/64), 256, 0, stream>>>(gb, ff_w2, fo, ROWS, DMODEL, DFF);
    final_kernel<1><<<(ROWS*DMODEL/4)/256, 256, 0, stream>>>(fo, 0, ff_b2, x, out);
  }
}

// Round 7
// 267.677 us; speedup vs baseline: 1.0047x; 1.0047x over previous
//
#include <hip/hip_runtime.h>
#include <hip/hip_bf16.h>
#include <math.h>

#define SEQ     512
#define BSZ     2
#define ROWS    (BSZ*SEQ)      // 1024
#define DMODEL  768
#define DINNER  1536
#define DSTATE  64
#define NHEADS  24
#define HEADDIM 64
#define CONVDIM 1664
#define DINPROJ 3224
#define DFF     3072
#define EPSF    1e-5f

typedef __attribute__((ext_vector_type(8))) short s16x8;   // 8 bf16 = 4 VGPRs
typedef __attribute__((ext_vector_type(4))) float f32x4;   // MFMA accumulator

__device__ __forceinline__ float b2f(const __hip_bfloat16 v){ return __bfloat162float(v); }
__device__ __forceinline__ __hip_bfloat16 f2b(float v){ return __float2bfloat16(v); }
__device__ __forceinline__ ushort f2bu(float v){
  union { __hip_bfloat16 b; ushort u; } c; c.b = __float2bfloat16(v); return c.u;
}
__device__ __forceinline__ float u2f(ushort u){ return __uint_as_float(((uint)u) << 16); }

// async global->LDS, 16B per lane; LDS dest = wave-uniform base + lane*16
__device__ __forceinline__ void gload16(const void* g, void* l){
  __builtin_amdgcn_global_load_lds((__attribute__((address_space(1))) const void*)g,
                                   (__attribute__((address_space(3))) void*)l, 16, 0, 0);
}

__device__ __forceinline__ float block_sum256(float v, float* sh){
  #pragma unroll
  for (int off = 32; off > 0; off >>= 1) v += __shfl_down(v, off, 64);
  int w = threadIdx.x >> 6;
  if ((threadIdx.x & 63) == 0) sh[w] = v;
  __syncthreads();
  float t = sh[0] + sh[1] + sh[2] + sh[3];
  __syncthreads();
  return t;
}

__global__ __launch_bounds__(256) void zerof_kernel(float* out, int n){
  int i = blockIdx.x*256 + threadIdx.x;
  if (i < n) out[i] = 0.f;
}

// ---- fused prep: [blocks < wblocks] all-weights fp32->bf16 ; [rest] ln1 ----
__global__ __launch_bounds__(256) void prep_kernel(const float* __restrict__ w0,
    const float* __restrict__ w1, const float* __restrict__ w2,
    const float* __restrict__ w3, ushort* __restrict__ o,
    int n0, int n1, int n2, int n3, int wblocks,
    const float* __restrict__ xin, const float* __restrict__ lnw,
    const float* __restrict__ lnb, __hip_bfloat16* __restrict__ xnout)
{
  __shared__ float sh[4];
  if ((int)blockIdx.x < wblocks){
    int i = (blockIdx.x*256 + threadIdx.x) << 2;
    int total = n0 + n1 + n2 + n3;
    if (i < total){
      const float* s; int off;
      if      (i < n0)       { s = w0; off = i; }
      else if (i < n0+n1)    { s = w1; off = i - n0; }
      else if (i < n0+n1+n2) { s = w2; off = i - n0 - n1; }
      else                   { s = w3; off = i - n0 - n1 - n2; }
      float4 f = *(const float4*)(s + off);
      *(ushort4*)(o + i) = make_ushort4(f2bu(f.x), f2bu(f.y), f2bu(f.z), f2bu(f.w));
    }
    return;
  }
  const int row = blockIdx.x - wblocks;
  const float* xr = xin + (size_t)row * DMODEL;
  float v[3]; float s = 0.f;
  #pragma unroll
  for (int i = 0; i < 3; i++){ int c = threadIdx.x + i*256; v[i] = xr[c]; s += v[i]; }
  s = block_sum256(s, sh);
  float mu = s * (1.f/DMODEL);
  float s2 = 0.f;
  #pragma unroll
  for (int i = 0; i < 3; i++){ float d = v[i]-mu; s2 += d*d; }
  s2 = block_sum256(s2, sh);
  float rs = rsqrtf(s2*(1.f/DMODEL) + EPSF);
  #pragma unroll
  for (int i = 0; i < 3; i++){
    int c = threadIdx.x + i*256;
    xnout[(size_t)row*DMODEL + c] = f2b((v[i]-mu)*rs*lnw[c] + lnb[c]);
  }
}

// ---- LayerNorm (fallback path) ----
__global__ __launch_bounds__(256) void ln_kernel(const float* __restrict__ in,
    const float* __restrict__ w, const float* __restrict__ b,
    __hip_bfloat16* __restrict__ out)
{
  __shared__ float sh[4];
  const int row = blockIdx.x;
  const float* xr = in + (size_t)row * DMODEL;
  float v[3]; float s = 0.f;
  #pragma unroll
  for (int i = 0; i < 3; i++){ int c = threadIdx.x + i*256; v[i] = xr[c]; s += v[i]; }
  s = block_sum256(s, sh);
  float mu = s * (1.f/DMODEL);
  float s2 = 0.f;
  #pragma unroll
  for (int i = 0; i < 3; i++){ float d = v[i]-mu; s2 += d*d; }
  s2 = block_sum256(s2, sh);
  float rs = rsqrtf(s2*(1.f/DMODEL) + EPSF);
  #pragma unroll
  for (int i = 0; i < 3; i++){
    int c = threadIdx.x + i*256;
    out[(size_t)row*DMODEL + c] = f2b((v[i]-mu)*rs*w[c] + b[c]);
  }
}

__device__ __forceinline__ s16x8 ld_frag(const ushort* p){
  union { ushort4 h[2]; s16x8 v; } u;
  u.h[0] = *(const ushort4*)(p);
  u.h[1] = *(const ushort4*)(p + 4);
  return u.v;
}

// ---- bf16 x bf16 MFMA GEMM, 64x64 tile, BK=64, gload_lds w16 ----
// 3-buffer pipeline, counted vmcnt(4), raw s_barrier.
// EPI: 0 = plain store, 1 = bias + exact GELU. KS>1: per-slice partials.
template<typename CTy, int KS, int EPI>
__global__ __launch_bounds__(256) void gemm_bb64(const __hip_bfloat16* __restrict__ A_,
    const __hip_bfloat16* __restrict__ B_, CTy* __restrict__ C,
    const float* __restrict__ bias, int M, int N, int K)
{
  __shared__ __align__(16) ushort As[3][64][64];
  __shared__ __align__(16) ushort Bs[3][64][64];
  const int tid  = threadIdx.x;
  const int lane = tid & 63, wave = tid >> 6;
  const int wr = wave >> 1, wc = wave & 1;        // 2x2 wave grid
  const int n0 = blockIdx.x * 64, m0 = blockIdx.y * 64;
  const int Kc   = K / KS;
  const int kbeg = blockIdx.z * Kc;
  const int NT   = Kc >> 6;                        // K-tiles (>= 3 for all calls)
  const int srw  = lane >> 3;                      // row-in-issue 0..7
  const int scol = (((lane & 7) ^ srw) << 3);      // swizzled src chunk (ushorts)
  const int l15  = lane & 15;
  const int r7   = l15 & 7;                        // frag row & 7 (i*16 preserves)
  const int c0   = lane >> 4;                      // frag chunk base 0..3

  const ushort* Au = (const ushort*)A_;
  const ushort* Bu = (const ushort*)B_;

  f32x4 acc[2][2] = {};

  auto stage = [&](int bf, int k0){
    #pragma unroll
    for (int q = 0; q < 2; q++){
      int row = q*32 + wave*8 + srw;
      gload16(Au + (size_t)(m0 + row)*K + kbeg + k0 + scol, &As[bf][q*32 + wave*8][0]);
      int nr = n0 + row; if (nr > N-1) nr = N-1;   // clamp; garbage cols never stored
      gload16(Bu + (size_t)nr*K + kbeg + k0 + scol, &Bs[bf][q*32 + wave*8][0]);
    }
  };

  stage(0, 0);
  stage(1, 64);
  asm volatile("s_waitcnt vmcnt(4)" ::: "memory");   // tile 0 landed (all 4 loads)
  __builtin_amdgcn_s_barrier();

  for (int t = 0; t < NT; ++t){
    const int nxt = t + 2;
    if (nxt < NT) stage(nxt % 3, nxt << 6);          // keep 2 tiles in flight
    const int cur = t % 3;
    #pragma unroll
    for (int tt = 0; tt < 2; tt++){
      const int fc = (((tt*4 + c0) ^ r7) << 3);      // swizzled frag col (ushorts)
      s16x8 a0 = ld_frag(&As[cur][wr*32      + l15][fc]);
      s16x8 a1 = ld_frag(&As[cur][wr*32 + 16 + l15][fc]);
      s16x8 b0 = ld_frag(&Bs[cur][wc*32      + l15][fc]);
      s16x8 b1 = ld_frag(&Bs[cur][wc*32 + 16 + l15][fc]);
      acc[0][0] = __builtin_amdgcn_mfma_f32_16x16x32_bf16(a0, b0, acc[0][0], 0, 0, 0);
      acc[0][1] = __builtin_amdgcn_mfma_f32_16x16x32_bf16(a0, b1, acc[0][1], 0, 0, 0);
      acc[1][0] = __builtin_amdgcn_mfma_f32_16x16x32_bf16(a1, b0, acc[1][0], 0, 0, 0);
      acc[1][1] = __builtin_amdgcn_mfma_f32_16x16x32_bf16(a1, b1, acc[1][1], 0, 0, 0);
    }
    if (t == NT-1) break;                            // no further reads
    if (nxt < NT) { asm volatile("s_waitcnt vmcnt(4)" ::: "memory"); }
    else          { asm volatile("s_waitcnt vmcnt(0)" ::: "memory"); }
    __builtin_amdgcn_s_barrier();
  }

  CTy* Cz = C + (size_t)blockIdx.z * M * N;
  // C/D layout (verified m89/m91): col = lane&15, row = (lane>>4)*4 + reg
  const int crow = (lane >> 4) * 4;
  #pragma unroll
  for (int i = 0; i < 2; i++){
    #pragma unroll
    for (int j = 0; j < 2; j++){
      int col = n0 + wc*32 + j*16 + l15;
      if (col < N){
        #pragma unroll
        for (int q = 0; q < 4; q++){
          int rowg = m0 + wr*32 + i*16 + crow + q;
          if constexpr (EPI == 1){
            float v = acc[i][j][q] + bias[col];
            Cz[(size_t)rowg*N + col] = (CTy)f2b(0.5f * v * (1.f + erff(v * 0.70710678118654752f)));
          } else if constexpr (sizeof(CTy) == 4){
            Cz[(size_t)rowg*N + col] = acc[i][j][q];
          } else {
            Cz[(size_t)rowg*N + col] = (CTy)f2b(acc[i][j][q]);
          }
        }
      }
    }
  }
}

// ---- fallback MFMA GEMM (fp32 B, 64x64 tile) -- used only if ws too small ----
template<typename CTy>
__global__ __launch_bounds__(256) void gemm_mfma(const __hip_bfloat16* __restrict__ A,
    const float* __restrict__ B, CTy* __restrict__ C, int M, int N, int K)
{
  __shared__ __align__(16) ushort As[64][72];
  __shared__ __align__(16) ushort Bs[64][72];
  const int tid  = threadIdx.x;
  const int lane = tid & 63, wave = tid >> 6;
  const int wr = wave >> 1, wc = wave & 1;
  const int n0 = blockIdx.x * 64, m0 = blockIdx.y * 64;
  const int sr = tid >> 2;
  const int sc = (tid & 3) * 16;
  const int l15 = lane & 15, lk = (lane >> 4) * 8;

  f32x4 acc[2][2] = {};

  const ushort* Au = (const ushort*)A;
  int nr = n0 + sr; if (nr > N-1) nr = N-1;

  for (int k0 = 0; k0 < K; k0 += 64){
    const ushort* ag = Au + (size_t)(m0 + sr)*K + (k0 + sc);
    ushort4 a0 = *(const ushort4*)(ag);
    ushort4 a1 = *(const ushort4*)(ag + 4);
    ushort4 a2 = *(const ushort4*)(ag + 8);
    ushort4 a3 = *(const ushort4*)(ag + 12);
    const float* bg = B + (size_t)nr*K + (k0 + sc);
    float4 f0 = *(const float4*)(bg);
    float4 f1 = *(const float4*)(bg + 4);
    float4 f2 = *(const float4*)(bg + 8);
    float4 f3 = *(const float4*)(bg + 12);
    ushort4 b0 = make_ushort4(f2bu(f0.x), f2bu(f0.y), f2bu(f0.z), f2bu(f0.w));
    ushort4 b1 = make_ushort4(f2bu(f1.x), f2bu(f1.y), f2bu(f1.z), f2bu(f1.w));
    ushort4 b2 = make_ushort4(f2bu(f2.x), f2bu(f2.y), f2bu(f2.z), f2bu(f2.w));
    ushort4 b3 = make_ushort4(f2bu(f3.x), f2bu(f3.y), f2bu(f3.z), f2bu(f3.w));

    __syncthreads();
    *(ushort4*)&As[sr][sc +  0] = a0;
    *(ushort4*)&As[sr][sc +  4] = a1;
    *(ushort4*)&As[sr][sc +  8] = a2;
    *(ushort4*)&As[sr][sc + 12] = a3;
    *(ushort4*)&Bs[sr][sc +  0] = b0;
    *(ushort4*)&Bs[sr][sc +  4] = b1;
    *(ushort4*)&Bs[sr][sc +  8] = b2;
    *(ushort4*)&Bs[sr][sc + 12] = b3;
    __syncthreads();

    #pragma unroll
    for (int kk = 0; kk < 64; kk += 32){
      s16x8 af0 = ld_frag(&As[wr*32      + l15][kk + lk]);
      s16x8 af1 = ld_frag(&As[wr*32 + 16 + l15][kk + lk]);
      s16x8 bf0 = ld_frag(&Bs[wc*32      + l15][kk + lk]);
      s16x8 bf1 = ld_frag(&Bs[wc*32 + 16 + l15][kk + lk]);
      acc[0][0] = __builtin_amdgcn_mfma_f32_16x16x32_bf16(af0, bf0, acc[0][0], 0, 0, 0);
      acc[0][1] = __builtin_amdgcn_mfma_f32_16x16x32_bf16(af0, bf1, acc[0][1], 0, 0, 0);
      acc[1][0] = __builtin_amdgcn_mfma_f32_16x16x32_bf16(af1, bf0, acc[1][0], 0, 0, 0);
      acc[1][1] = __builtin_amdgcn_mfma_f32_16x16x32_bf16(af1, bf1, acc[1][1], 0, 0, 0);
    }
  }

  const int crow = (lane >> 4) * 4;
  #pragma unroll
  for (int i = 0; i < 2; i++){
    #pragma unroll
    for (int j = 0; j < 2; j++){
      int col = n0 + wc*32 + j*16 + l15;
      if (col < N){
        #pragma unroll
        for (int q = 0; q < 4; q++){
          int rowg = m0 + wr*32 + i*16 + crow + q;
          if constexpr (sizeof(CTy) == 4) C[(size_t)rowg*N + col] = acc[i][j][q];
          else                            C[(size_t)rowg*N + col] = (CTy)f2b(acc[i][j][q]);
        }
      }
    }
  }
}

// ---- causal depthwise conv(4) + bias + silu (both dirs) + dt/dA prep ----
__global__ __launch_bounds__(256) void convdt_kernel(const __hip_bfloat16* __restrict__ zx,
    const float* __restrict__ cw, const float* __restrict__ cb,
    const float* __restrict__ dt_bias, const float* __restrict__ A_log,
    __hip_bfloat16* __restrict__ xconv, float* __restrict__ dtb, float* __restrict__ dab)
{
  const int tt = blockIdx.x, b = blockIdx.y, dir = blockIdx.z;
  const int c8 = threadIdx.x * 8;
  if (c8 < CONVDIM){
    size_t rowoff[4]; bool ok[4];
    #pragma unroll
    for (int k = 0; k < 4; k++){
      int s = tt - 3 + k;
      ok[k] = (s >= 0);
      int ss = ok[k] ? s : 0;
      int phys = dir ? (SEQ-1-ss) : ss;
      rowoff[k] = ((size_t)(b*SEQ + phys))*DINPROJ + DINNER + c8;
    }
    float acc[8];
    {
      float4 cb0 = *(const float4*)(cb + c8);
      float4 cb1 = *(const float4*)(cb + c8 + 4);
      acc[0]=cb0.x; acc[1]=cb0.y; acc[2]=cb0.z; acc[3]=cb0.w;
      acc[4]=cb1.x; acc[5]=cb1.y; acc[6]=cb1.z; acc[7]=cb1.w;
    }
    float wv[8][4];
    #pragma unroll
    for (int j = 0; j < 8; j++){
      float4 w4 = *(const float4*)(cw + (size_t)(c8 + j)*4);
      wv[j][0]=w4.x; wv[j][1]=w4.y; wv[j][2]=w4.z; wv[j][3]=w4.w;
    }
    const ushort* zu = (const ushort*)zx;
    #pragma unroll
    for (int k = 0; k < 4; k++){
      if (ok[k]){
        ushort4 v0 = *(const ushort4*)(zu + rowoff[k]);
        ushort4 v1 = *(const ushort4*)(zu + rowoff[k] + 4);
        acc[0] = fmaf(wv[0][k], u2f(v0.x), acc[0]);
        acc[1] = fmaf(wv[1][k], u2f(v0.y), acc[1]);
        acc[2] = fmaf(wv[2][k], u2f(v0.z), acc[2]);
        acc[3] = fmaf(wv[3][k], u2f(v0.w), acc[3]);
        acc[4] = fmaf(wv[4][k], u2f(v1.x), acc[4]);
        acc[5] = fmaf(wv[5][k], u2f(v1.y), acc[5]);
        acc[6] = fmaf(wv[6][k], u2f(v1.z), acc[6]);
        acc[7] = fmaf(wv[7][k], u2f(v1.w), acc[7]);
      }
    }
    ushort* outr = (ushort*)xconv + ((size_t)((dir*BSZ + b)*SEQ + tt))*CONVDIM + c8;
    ushort o[8];
    #pragma unroll
    for (int j = 0; j < 8; j++){
      float s = acc[j] / (1.f + expf(-acc[j]));   // silu
      o[j] = f2bu(s);
    }
    *(ushort4*)(outr)     = make_ushort4(o[0],o[1],o[2],o[3]);
    *(ushort4*)(outr + 4) = make_ushort4(o[4],o[5],o[6],o[7]);
  }
  if (dir == 0 && threadIdx.x < NHEADS){
    int h = threadIdx.x;
    size_t r = (size_t)b*SEQ + tt;
    float raw = b2f(zx[r*DINPROJ + (DINNER + CONVDIM) + h]) + dt_bias[h];
    float sp  = fmaxf(raw, 0.f) + log1pf(expf(-fabsf(raw)));   // stable softplus
    dtb[r*NHEADS + h] = sp;
    dab[r*NHEADS + h] = expf(-sp * expf(A_log[h]));
  }
}

// ======================= chunked selective scan =======================
#define CT 16

// pass1: local chunk scan, state update only. grid (NC-1, NHEADS, 4)
__global__ __launch_bounds__(256) void scan_pass1(const __hip_bfloat16* __restrict__ xconv,
    const float* __restrict__ dtb, const float* __restrict__ dab,
    float* __restrict__ stateBuf, int CL)
{
  const int c = blockIdx.x, h = blockIdx.y, z = blockIdx.z;
  const int b = z & 1, dir = z >> 1;
  const int tid = threadIdx.x, lane = tid & 63, wave = tid >> 6, nb = wave * 16;
  __shared__ __align__(16) float Bc[CT][64], Xc[CT][64];
  __shared__ float dAc[CT], dtc[CT];
  float hreg[16];
  #pragma unroll
  for (int j = 0; j < 16; j++) hreg[j] = 0.f;
  const size_t dirbase = (size_t)z * SEQ;
  const int cstart = c * CL;

  const int ttl = tid >> 4, c4 = (tid & 15) << 2;

  for (int c0 = cstart; c0 < cstart + CL; c0 += CT){
    {
      const ushort* rowp = (const ushort*)xconv + (dirbase + c0 + ttl)*(size_t)CONVDIM;
      ushort4 bv = *(const ushort4*)(rowp + DINNER + c4);
      ushort4 xv = *(const ushort4*)(rowp + h*HEADDIM + c4);
      Bc[ttl][c4+0] = u2f(bv.x); Bc[ttl][c4+1] = u2f(bv.y);
      Bc[ttl][c4+2] = u2f(bv.z); Bc[ttl][c4+3] = u2f(bv.w);
      Xc[ttl][c4+0] = u2f(xv.x); Xc[ttl][c4+1] = u2f(xv.y);
      Xc[ttl][c4+2] = u2f(xv.z); Xc[ttl][c4+3] = u2f(xv.w);
    }
    if (tid < CT){
      int phys = dir ? (SEQ-1 - (c0 + tid)) : (c0 + tid);
      size_t r = (size_t)b*SEQ + phys;
      dAc[tid] = dab[r*NHEADS + h];
      dtc[tid] = dtb[r*NHEADS + h];
    }
    __syncthreads();

    #pragma unroll 4
    for (int tt = 0; tt < CT; tt++){
      float dA = dAc[tt];
      float dtx = dtc[tt] * Xc[tt][lane];
      const float4* Bq = (const float4*)&Bc[tt][nb];
      float4 B0 = Bq[0], B1 = Bq[1], B2 = Bq[2], B3 = Bq[3];
      hreg[ 0]=fmaf(dA,hreg[ 0],dtx*B0.x); hreg[ 1]=fmaf(dA,hreg[ 1],dtx*B0.y);
      hreg[ 2]=fmaf(dA,hreg[ 2],dtx*B0.z); hreg[ 3]=fmaf(dA,hreg[ 3],dtx*B0.w);
      hreg[ 4]=fmaf(dA,hreg[ 4],dtx*B1.x); hreg[ 5]=fmaf(dA,hreg[ 5],dtx*B1.y);
      hreg[ 6]=fmaf(dA,hreg[ 6],dtx*B1.z); hreg[ 7]=fmaf(dA,hreg[ 7],dtx*B1.w);
      hreg[ 8]=fmaf(dA,hreg[ 8],dtx*B2.x); hreg[ 9]=fmaf(dA,hreg[ 9],dtx*B2.y);
      hreg[10]=fmaf(dA,hreg[10],dtx*B2.z); hreg[11]=fmaf(dA,hreg[11],dtx*B2.w);
      hreg[12]=fmaf(dA,hreg[12],dtx*B3.x); hreg[13]=fmaf(dA,hreg[13],dtx*B3.y);
      hreg[14]=fmaf(dA,hreg[14],dtx*B3.z); hreg[15]=fmaf(dA,hreg[15],dtx*B3.w);
    }
    __syncthreads();
  }

  float* sp = stateBuf + (((size_t)c*4 + z)*NHEADS + h)*4096 + (size_t)lane*64 + nb;
  *(float4*)(sp +  0) = make_float4(hreg[ 0],hreg[ 1],hreg[ 2],hreg[ 3]);
  *(float4*)(sp +  4) = make_float4(hreg[ 4],hreg[ 5],hreg[ 6],hreg[ 7]);
  *(float4*)(sp +  8) = make_float4(hreg[ 8],hreg[ 9],hreg[10],hreg[11]);
  *(float4*)(sp + 12) = make_float4(hreg[12],hreg[13],hreg[14],hreg[15]);
}

// fixup: h_init[c] = P_{c-1} h_init[c-1] + L_{c-1}; overwrites state[c] (c>=1).
// grid (NHEADS, 4); supports NC up to 16.
__global__ __launch_bounds__(256) void scan_fixup(const float* __restrict__ dab,
    float* __restrict__ stateBuf, int NC, int CL)
{
  const int h = blockIdx.x, z = blockIdx.y;
  const int b = z & 1, dir = z >> 1;
  const int tid = threadIdx.x;
  __shared__ float sdA[SEQ];
  __shared__ float P[16];
  for (int i = tid; i < SEQ; i += 256){
    int phys = dir ? (SEQ-1-i) : i;
    sdA[i] = dab[((size_t)b*SEQ + phys)*NHEADS + h];
  }
  __syncthreads();
  if (tid < NC){
    float p = 1.f;
    for (int i = 0; i < CL; i++) p *= sdA[tid*CL + i];
    P[tid] = p;
  }
  __syncthreads();

  float hrun[16], Lcur[16];
  #pragma unroll
  for (int j = 0; j < 16; j++) hrun[j] = 0.f;
  {
    const float* s0 = stateBuf + ((size_t)z*NHEADS + h)*4096 + (size_t)tid*16;
    #pragma unroll
    for (int j = 0; j < 16; j++) Lcur[j] = s0[j];
  }
  for (int c = 1; c < NC; c++){
    float Pp = P[c-1];
    float hnew[16];
    #pragma unroll
    for (int j = 0; j < 16; j++) hnew[j] = fmaf(Pp, hrun[j], Lcur[j]);
    float* sc = stateBuf + (((size_t)c*4 + z)*NHEADS + h)*4096 + (size_t)tid*16;
    if (c < NC-1){
      #pragma unroll
      for (int j = 0; j < 16; j++) Lcur[j] = sc[j];   // read L_c before overwrite
    }
    #pragma unroll
    for (int j = 0; j < 16; j++) sc[j] = hnew[j];
    #pragma unroll
    for (int j = 0; j < 16; j++) hrun[j] = hnew[j];
  }
}

// pass2: full scan per chunk from h_init. grid (NC, NHEADS, 4)
__global__ __launch_bounds__(256) void scan_pass2(const __hip_bfloat16* __restrict__ xconv,
    const __hip_bfloat16* __restrict__ zx, const float* __restrict__ dtb,
    const float* __restrict__ dab, const float* __restrict__ Dp,
    const float* __restrict__ stateBuf, __hip_bfloat16* __restrict__ yg, int CL)
{
  const int c = blockIdx.x, h = blockIdx.y, z = blockIdx.z;
  const int b = z & 1, dir = z >> 1;
  const int tid = threadIdx.x, lane = tid & 63, wave = tid >> 6, nb = wave * 16;
  __shared__ __align__(16) float Bc[CT][64], Cc[CT][64], Xc[CT][64];
  __shared__ __align__(16) float Yp[4][CT][64];
  __shared__ float dAc[CT], dtc[CT];
  float hreg[16];
  if (c == 0){
    #pragma unroll
    for (int j = 0; j < 16; j++) hreg[j] = 0.f;
  } else {
    const float* sp = stateBuf + (((size_t)c*4 + z)*NHEADS + h)*4096 + (size_t)lane*64 + nb;
    float4 s0 = *(const float4*)(sp+0), s1 = *(const float4*)(sp+4);
    float4 s2 = *(const float4*)(sp+8), s3 = *(const float4*)(sp+12);
    hreg[ 0]=s0.x; hreg[ 1]=s0.y; hreg[ 2]=s0.z; hreg[ 3]=s0.w;
    hreg[ 4]=s1.x; hreg[ 5]=s1.y; hreg[ 6]=s1.z; hreg[ 7]=s1.w;
    hreg[ 8]=s2.x; hreg[ 9]=s2.y; hreg[10]=s2.z; hreg[11]=s2.w;
    hreg[12]=s3.x; hreg[13]=s3.y; hreg[14]=s3.z; hreg[15]=s3.w;
  }
  const float Dh = Dp[h];
  const size_t dirbase = (size_t)z * SEQ;
  const int cstart = c * CL;
  const int ttl = tid >> 4, c4 = (tid & 15) << 2;

  for (int c0 = cstart; c0 < cstart + CL; c0 += CT){
    {
      const ushort* rowp = (const ushort*)xconv + (dirbase + c0 + ttl)*(size_t)CONVDIM;
      ushort4 bv = *(const ushort4*)(rowp + DINNER + c4);
      ushort4 cv = *(const ushort4*)(rowp + DINNER + DSTATE + c4);
      ushort4 xv = *(const ushort4*)(rowp + h*HEADDIM + c4);
      Bc[ttl][c4+0] = u2f(bv.x); Bc[ttl][c4+1] = u2f(bv.y);
      Bc[ttl][c4+2] = u2f(bv.z); Bc[ttl][c4+3] = u2f(bv.w);
      Cc[ttl][c4+0] = u2f(cv.x); Cc[ttl][c4+1] = u2f(cv.y);
      Cc[ttl][c4+2] = u2f(cv.z); Cc[ttl][c4+3] = u2f(cv.w);
      Xc[ttl][c4+0] = u2f(xv.x); Xc[ttl][c4+1] = u2f(xv.y);
      Xc[ttl][c4+2] = u2f(xv.z); Xc[ttl][c4+3] = u2f(xv.w);
    }
    if (tid < CT){
      int phys = dir ? (SEQ-1 - (c0 + tid)) : (c0 + tid);
      size_t r = (size_t)b*SEQ + phys;
      dAc[tid] = dab[r*NHEADS + h];
      dtc[tid] = dtb[r*NHEADS + h];
    }
    __syncthreads();

    #pragma unroll 4
    for (int tt = 0; tt < CT; tt++){
      float dA = dAc[tt];
      float dtx = dtc[tt] * Xc[tt][lane];
      const float4* Bq = (const float4*)&Bc[tt][nb];
      const float4* Cq = (const float4*)&Cc[tt][nb];
      float4 B0 = Bq[0], B1 = Bq[1], B2 = Bq[2], B3 = Bq[3];
      float4 C0 = Cq[0], C1 = Cq[1], C2 = Cq[2], C3 = Cq[3];
      float y0 = 0.f, y1 = 0.f, y2 = 0.f, y3 = 0.f;
      hreg[ 0]=fmaf(dA,hreg[ 0],dtx*B0.x); y0=fmaf(hreg[ 0],C0.x,y0);
      hreg[ 1]=fmaf(dA,hreg[ 1],dtx*B0.y); y1=fmaf(hreg[ 1],C0.y,y1);
      hreg[ 2]=fmaf(dA,hreg[ 2],dtx*B0.z); y2=fmaf(hreg[ 2],C0.z,y2);
      hreg[ 3]=fmaf(dA,hreg[ 3],dtx*B0.w); y3=fmaf(hreg[ 3],C0.w,y3);
      hreg[ 4]=fmaf(dA,hreg[ 4],dtx*B1.x); y0=fmaf(hreg[ 4],C1.x,y0);
      hreg[ 5]=fmaf(dA,hreg[ 5],dtx*B1.y); y1=fmaf(hreg[ 5],C1.y,y1);
      hreg[ 6]=fmaf(dA,hreg[ 6],dtx*B1.z); y2=fmaf(hreg[ 6],C1.z,y2);
      hreg[ 7]=fmaf(dA,hreg[ 7],dtx*B1.w); y3=fmaf(hreg[ 7],C1.w,y3);
      hreg[ 8]=fmaf(dA,hreg[ 8],dtx*B2.x); y0=fmaf(hreg[ 8],C2.x,y0);
      hreg[ 9]=fmaf(dA,hreg[ 9],dtx*B2.y); y1=fmaf(hreg[ 9],C2.y,y1);
      hreg[10]=fmaf(dA,hreg[10],dtx*B2.z); y2=fmaf(hreg[10],C2.z,y2);
      hreg[11]=fmaf(dA,hreg[11],dtx*B2.w); y3=fmaf(hreg[11],C2.w,y3);
      hreg[12]=fmaf(dA,hreg[12],dtx*B3.x); y0=fmaf(hreg[12],C3.x,y0);
      hreg[13]=fmaf(dA,hreg[13],dtx*B3.y); y1=fmaf(hreg[13],C3.y,y1);
      hreg[14]=fmaf(dA,hreg[14],dtx*B3.z); y2=fmaf(hreg[14],C3.z,y2);
      hreg[15]=fmaf(dA,hreg[15],dtx*B3.w); y3=fmaf(hreg[15],C3.w,y3);
      Yp[wave][tt][lane] = (y0+y1) + (y2+y3);
    }
    __syncthreads();

    {
      // vectorized epilogue: 4 consecutive p per thread
      int tl = tid >> 4, p4 = (tid & 15) << 2;
      float4 ya = *(const float4*)&Yp[0][tl][p4];
      float4 yb4 = *(const float4*)&Yp[1][tl][p4];
      float4 yc = *(const float4*)&Yp[2][tl][p4];
      float4 yd = *(const float4*)&Yp[3][tl][p4];
      float4 xv = *(const float4*)&Xc[tl][p4];
      int phys = dir ? (SEQ-1 - (c0 + tl)) : (c0 + tl);
      size_t r = (size_t)b*SEQ + phys;
      const ushort* zp = (const ushort*)zx + r*DINPROJ + h*HEADDIM + p4;
      ushort4 zv = *(const ushort4*)zp;
      float zf[4] = { u2f(zv.x), u2f(zv.y), u2f(zv.z), u2f(zv.w) };
      float yv[4] = { ya.x+yb4.x+yc.x+yd.x + Dh*xv.x,
                      ya.y+yb4.y+yc.y+yd.y + Dh*xv.y,
                      ya.z+yb4.z+yc.z+yd.z + Dh*xv.z,
                      ya.w+yb4.w+yc.w+yd.w + Dh*xv.w };
      ushort o[4];
      #pragma unroll
      for (int j = 0; j < 4; j++){
        float sil = zf[j] / (1.f + expf(-zf[j]));
        o[j] = f2bu(yv[j] * sil);
      }
      ushort* op = (ushort*)yg + ((size_t)dir*ROWS + r)*DINNER + h*HEADDIM + p4;
      *(ushort4*)op = make_ushort4(o[0],o[1],o[2],o[3]);
    }
    __syncthreads();
  }
}

// ---- per-row gated RMSNorm both dirs + combine (fp32 norm_w) -> u bf16 ----
__global__ __launch_bounds__(256) void rmscomb_kernel(const __hip_bfloat16* __restrict__ yg,
    const float* __restrict__ nw, __hip_bfloat16* __restrict__ u)
{
  __shared__ float sh[4];
  const int row = blockIdx.x;
  const __hip_bfloat16* yf = yg + (size_t)row*DINNER;
  const __hip_bfloat16* yb = yg + (size_t)(ROWS + row)*DINNER;
  float vf[6], vb[6]; float sf = 0.f, sb = 0.f;
  #pragma unroll
  for (int i = 0; i < 6; i++){
    int c = threadIdx.x + i*256;
    vf[i] = b2f(yf[c]); sf += vf[i]*vf[i];
    vb[i] = b2f(yb[c]); sb += vb[i]*vb[i];
  }
  sf = block_sum256(sf, sh);
  sb = block_sum256(sb, sh);
  float rf = rsqrtf(sf*(1.f/DINNER) + EPSF);
  float rb = rsqrtf(sb*(1.f/DINNER) + EPSF);
  #pragma unroll
  for (int i = 0; i < 6; i++){
    int c = threadIdx.x + i*256;
    u[(size_t)row*DINNER + c] = f2b((vf[i]*rf + vb[i]*rb) * nw[c]);
  }
}

// ---- ln2 on NP fp32 partials -> bf16 mb ----
template<int NP>
__global__ __launch_bounds__(256) void ln2_kernel(const float* __restrict__ in,
    size_t pstride, const float* __restrict__ w, const float* __restrict__ b,
    __hip_bfloat16* __restrict__ out)
{
  __shared__ float sh[4];
  const int row = blockIdx.x;
  float v[3]; float s = 0.f;
  #pragma unroll
  for (int i = 0; i < 3; i++){
    int c = threadIdx.x + i*256;
    size_t idx = (size_t)row*DMODEL + c;
    float t = 0.f;
    #pragma unroll
    for (int p = 0; p < NP; p++) t += in[p*pstride + idx];
    v[i] = t; s += t;
  }
  s = block_sum256(s, sh);
  float mu = s * (1.f/DMODEL);
  float s2 = 0.f;
  #pragma unroll
  for (int i = 0; i < 3; i++){ float d = v[i]-mu; s2 += d*d; }
  s2 = block_sum256(s2, sh);
  float rs = rsqrtf(s2*(1.f/DMODEL) + EPSF);
  #pragma unroll
  for (int i = 0; i < 3; i++){
    int c = threadIdx.x + i*256;
    out[(size_t)row*DMODEL + c] = f2b((v[i]-mu)*rs*w[c] + b[c]);
  }
}

// ---- exact GELU with fp32 bias (fallback path only) ----
__global__ __launch_bounds__(256) void gelu_kernel(const __hip_bfloat16* __restrict__ g,
    const float* __restrict__ b1, __hip_bfloat16* __restrict__ out)
{
  size_t idx = (size_t)blockIdx.x*256 + threadIdx.x;
  int c = (int)(idx % DFF);
  float v = b2f(g[idx]) + b1[c];
  out[idx] = f2b(0.5f * v * (1.f + erff(v * 0.70710678118654752f)));
}

// ---- final: sum NP fp32 partials + bias + residual -> fp32 out (x4 vec) ----
template<int NP>
__global__ __launch_bounds__(256) void final_kernel(const float* __restrict__ f,
    size_t pstride, const float* __restrict__ bias, const float* __restrict__ x,
    float* __restrict__ out)
{
  size_t i4 = ((size_t)blockIdx.x*256 + threadIdx.x) << 2;
  int c = (int)(i4 % DMODEL);
  float4 bv = *(const float4*)(bias + c);
  float4 xv = *(const float4*)(x + i4);
  float4 s = make_float4(bv.x+xv.x, bv.y+xv.y, bv.z+xv.z, bv.w+xv.w);
  #pragma unroll
  for (int p = 0; p < NP; p++){
    float4 fv = *(const float4*)(f + p*pstride + i4);
    s.x += fv.x; s.y += fv.y; s.z += fv.z; s.w += fv.w;
  }
  *(float4*)(out + i4) = s;
}

extern "C" void kernel_launch(void* const* d_in, const int* in_sizes, int n_in,
                              void* d_out, int out_size, void* d_ws, size_t ws_size,
                              hipStream_t stream)
{
  float* out = (float*)d_out;

  const size_t NEED = 19906560;   // base plan (proven to fit)
  if (ws_size < NEED || n_in < 17){
    zerof_kernel<<<(out_size + 255)/256, 256, 0, stream>>>(out, out_size);
    return;
  }

  const float* x       = (const float*)d_in[0];
  const float* in_proj_w = (const float*)d_in[1];
  const float* conv_w  = (const float*)d_in[2];
  const float* conv_b  = (const float*)d_in[3];
  const float* dt_bias = (const float*)d_in[4];
  const float* A_log   = (const float*)d_in[5];
  const float* D_param = (const float*)d_in[6];
  const float* norm_w  = (const float*)d_in[7];
  const float* out_proj_w = (const float*)d_in[8];
  const float* ln1_w   = (const float*)d_in[9];
  const float* ln1_b   = (const float*)d_in[10];
  const float* ln2_w   = (const float*)d_in[11];
  const float* ln2_b   = (const float*)d_in[12];
  const float* ff_w1   = (const float*)d_in[13];
  const float* ff_b1   = (const float*)d_in[14];
  const float* ff_w2   = (const float*)d_in[15];
  const float* ff_b2   = (const float*)d_in[16];

  char* ws = (char*)d_ws;
  __hip_bfloat16* zx  = (__hip_bfloat16*)(ws + 0);         // 6,602,752
  __hip_bfloat16* xn  = (__hip_bfloat16*)(ws + 6602752);   // 1,572,864 (dead after s2)
  float*          dtb = (float*)(ws + 6602752);            //    98,304 (over xn)
  float*          dab = (float*)(ws + 6701056);            //    98,304
  __hip_bfloat16* xcv = (__hip_bfloat16*)(ws + 6799360);   // 6,815,744 -> 13,615,104
  __hip_bfloat16* yg  = (__hip_bfloat16*)(ws + 13615104);  // 6,291,456 -> 19,906,560
  __hip_bfloat16* u   = (__hip_bfloat16*)(ws + 0);         // over zx (dead after scan)
  float*          mo  = (float*)(ws + 3145728);            // over zx (fallback)
  __hip_bfloat16* mb  = (__hip_bfloat16*)(ws + 0);         // over u (dead)
  __hip_bfloat16* g   = (__hip_bfloat16*)(ws + 6799360);   // over xcv (fallback)
  __hip_bfloat16* gb  = (__hip_bfloat16*)(ws + 13615104);  // over yg (dead)
  float*          fo  = (float*)(ws + 0);                  // over mb (fallback)

  // fast-path extra regions beyond base plan (ws observed ~268 MB):
  const size_t WBALL = 16748544;        // all 4 weight matrices bf16
  const size_t PARTS = 12582912;        // 4 fp32 partials of ROWS*DMODEL
  const size_t CHB   = 1572864;         // per-chunk scan states
  const size_t PSTRIDE = (size_t)ROWS * DMODEL;
  const int WN_IN  = DINPROJ*DMODEL;    // 2,476,032
  const int WN_OUT = DMODEL*DINNER;     // 1,179,648
  const int WN_F1  = DFF*DMODEL;        // 2,359,296
  const int WN_F2  = DMODEL*DFF;        // 2,359,296

  size_t rem = ws_size - NEED;
  bool fast = (rem >= WBALL + PARTS);
  ushort* wb    = (ushort*)(ws + NEED);
  float*  parts = (float*) (ws + NEED + WBALL);
  size_t scanoff = NEED + (fast ? (WBALL + PARTS) : 0);
  size_t srem = ws_size - scanoff;
  int NC = 1;
  if      (srem >= 16*CHB) NC = 16;
  else if (srem >=  8*CHB) NC = 8;
  else if (srem >=  4*CHB) NC = 4;
  else if (srem >=  2*CHB) NC = 2;
  float* stateBuf = (float*)(ws + scanoff);
  const int CL = SEQ / NC;

  if (fast){
    // 1+2) fused: weight conversion (all 4) + ln1
    const int wblocks = (WN_IN + WN_OUT + WN_F1 + WN_F2) / 4 / 256;   // 8178 exact
    prep_kernel<<<wblocks + ROWS, 256, 0, stream>>>(in_proj_w, out_proj_w, ff_w1, ff_w2,
        wb, WN_IN, WN_OUT, WN_F1, WN_F2, wblocks, x, ln1_w, ln1_b, xn);
    // 3) in_proj -> zx bf16
    gemm_bb64<__hip_bfloat16,1,0><<<dim3((DINPROJ+63)/64, ROWS/64), 256, 0, stream>>>(
        xn, (const __hip_bfloat16*)wb, zx, nullptr, ROWS, DINPROJ, DMODEL);
  } else {
    ln_kernel<<<ROWS, 256, 0, stream>>>(x, ln1_w, ln1_b, xn);
    gemm_mfma<<<dim3((DINPROJ+63)/64, ROWS/64), 256, 0, stream>>>(xn, in_proj_w, zx, ROWS, DINPROJ, DMODEL);
  }
  // 4) conv + silu + dt/dA
  convdt_kernel<<<dim3(SEQ, BSZ, 2), 256, 0, stream>>>(zx, conv_w, conv_b, dt_bias, A_log, xcv, dtb, dab);
  // 5) chunked scan (separate tiny fixup kernel; pass2 reads one state)
  if (NC > 1){
    scan_pass1<<<dim3(NC-1, NHEADS, 4), 256, 0, stream>>>(xcv, dtb, dab, stateBuf, CL);
    scan_fixup<<<dim3(NHEADS, 4), 256, 0, stream>>>(dab, stateBuf, NC, CL);
  }
  scan_pass2<<<dim3(NC, NHEADS, 4), 256, 0, stream>>>(xcv, zx, dtb, dab, D_param, stateBuf, yg, CL);
  // 6) per-dir RMS + combine -> u
  rmscomb_kernel<<<ROWS, 256, 0, stream>>>(yg, norm_w, u);
  // 7) out_proj [split-K=2, partials] ; 8) ln2 sums partials
  if (fast){
    gemm_bb64<float,2,0><<<dim3(DMODEL/64, ROWS/64, 2), 256, 0, stream>>>(
        u, (const __hip_bfloat16*)(wb + WN_IN), parts, nullptr, ROWS, DMODEL, DINNER);
    ln2_kernel<2><<<ROWS, 256, 0, stream>>>(parts, PSTRIDE, ln2_w, ln2_b, mb);
  } else {
    gemm_mfma<<<dim3(DMODEL/64, ROWS/64), 256, 0, stream>>>(u, out_proj_w, mo, ROWS, DMODEL, DINNER);
    ln2_kernel<1><<<ROWS, 256, 0, stream>>>(mo, 0, ln2_w, ln2_b, mb);
  }
  // 9) ff1 (+bias+gelu fused) -> gb
  if (fast){
    gemm_bb64<__hip_bfloat16,1,1><<<dim3(DFF/64, ROWS/64), 256, 0, stream>>>(
        mb, (const __hip_bfloat16*)(wb + WN_IN + WN_OUT), gb, ff_b1, ROWS, DFF, DMODEL);
  } else {
    gemm_mfma<<<dim3(DFF/64, ROWS/64), 256, 0, stream>>>(mb, ff_w1, g, ROWS, DFF, DMODEL);
    gelu_kernel<<<(ROWS*DFF)/256, 256, 0, stream>>>(g, ff_b1, gb);
  }
  // 10) ff2 [split-K=4, partials] ; 11) final sums + bias + residual
  if (fast){
    gemm_bb64<float,4,0><<<dim3(DMODEL/64, ROWS/64, 4), 256, 0, stream>>>(
        gb, (const __hip_bfloat16*)(wb + WN_IN + WN_OUT + WN_F1), parts, nullptr, ROWS, DMODEL, DFF);
    final_kernel<4><<<(ROWS*DMODEL/4)/256, 256, 0, stream>>>(parts, PSTRIDE, ff_b2, x, out);
  } else {
    gemm_mfma<<<dim3(DMODEL/64, ROWS/64), 256, 0, stream>>>(gb, ff_w2, fo, ROWS, DMODEL, DFF);
    final_kernel<1><<<(ROWS*DMODEL/4)/256, 256, 0, stream>>>(fo, 0, ff_b2, x, out);
  }
}

// Round 8
// 250.464 us; speedup vs baseline: 1.0737x; 1.0687x over previous
//
#include <hip/hip_runtime.h>
#include <hip/hip_bf16.h>
#include <math.h>

#define SEQ     512
#define BSZ     2
#define ROWS    (BSZ*SEQ)      // 1024
#define DMODEL  768
#define DINNER  1536
#define DSTATE  64
#define NHEADS  24
#define HEADDIM 64
#define CONVDIM 1664
#define DINPROJ 3224
#define DFF     3072
#define EPSF    1e-5f

typedef __attribute__((ext_vector_type(8))) short s16x8;   // 8 bf16 = 4 VGPRs
typedef __attribute__((ext_vector_type(4))) float f32x4;   // MFMA accumulator

__device__ __forceinline__ float b2f(const __hip_bfloat16 v){ return __bfloat162float(v); }
__device__ __forceinline__ __hip_bfloat16 f2b(float v){ return __float2bfloat16(v); }
__device__ __forceinline__ ushort f2bu(float v){
  union { __hip_bfloat16 b; ushort u; } c; c.b = __float2bfloat16(v); return c.u;
}
__device__ __forceinline__ float u2f(ushort u){ return __uint_as_float(((uint)u) << 16); }

// async global->LDS, 16B per lane; LDS dest = wave-uniform base + lane*16
__device__ __forceinline__ void gload16(const void* g, void* l){
  __builtin_amdgcn_global_load_lds((__attribute__((address_space(1))) const void*)g,
                                   (__attribute__((address_space(3))) void*)l, 16, 0, 0);
}

__device__ __forceinline__ float block_sum256(float v, float* sh){
  #pragma unroll
  for (int off = 32; off > 0; off >>= 1) v += __shfl_down(v, off, 64);
  int w = threadIdx.x >> 6;
  if ((threadIdx.x & 63) == 0) sh[w] = v;
  __syncthreads();
  float t = sh[0] + sh[1] + sh[2] + sh[3];
  __syncthreads();
  return t;
}

__global__ __launch_bounds__(256) void zerof_kernel(float* out, int n){
  int i = blockIdx.x*256 + threadIdx.x;
  if (i < n) out[i] = 0.f;
}

// ---- fused prep: [blocks < wblocks] all-weights fp32->bf16 ; [rest] ln1 ----
__global__ __launch_bounds__(256) void prep_kernel(const float* __restrict__ w0,
    const float* __restrict__ w1, const float* __restrict__ w2,
    const float* __restrict__ w3, ushort* __restrict__ o,
    int n0, int n1, int n2, int n3, int wblocks,
    const float* __restrict__ xin, const float* __restrict__ lnw,
    const float* __restrict__ lnb, __hip_bfloat16* __restrict__ xnout)
{
  __shared__ float sh[4];
  if ((int)blockIdx.x < wblocks){
    int i = (blockIdx.x*256 + threadIdx.x) << 2;
    int total = n0 + n1 + n2 + n3;
    if (i < total){
      const float* s; int off;
      if      (i < n0)       { s = w0; off = i; }
      else if (i < n0+n1)    { s = w1; off = i - n0; }
      else if (i < n0+n1+n2) { s = w2; off = i - n0 - n1; }
      else                   { s = w3; off = i - n0 - n1 - n2; }
      float4 f = *(const float4*)(s + off);
      *(ushort4*)(o + i) = make_ushort4(f2bu(f.x), f2bu(f.y), f2bu(f.z), f2bu(f.w));
    }
    return;
  }
  const int row = blockIdx.x - wblocks;
  const float* xr = xin + (size_t)row * DMODEL;
  float v[3]; float s = 0.f;
  #pragma unroll
  for (int i = 0; i < 3; i++){ int c = threadIdx.x + i*256; v[i] = xr[c]; s += v[i]; }
  s = block_sum256(s, sh);
  float mu = s * (1.f/DMODEL);
  float s2 = 0.f;
  #pragma unroll
  for (int i = 0; i < 3; i++){ float d = v[i]-mu; s2 += d*d; }
  s2 = block_sum256(s2, sh);
  float rs = rsqrtf(s2*(1.f/DMODEL) + EPSF);
  #pragma unroll
  for (int i = 0; i < 3; i++){
    int c = threadIdx.x + i*256;
    xnout[(size_t)row*DMODEL + c] = f2b((v[i]-mu)*rs*lnw[c] + lnb[c]);
  }
}

// ---- LayerNorm (fallback path) ----
__global__ __launch_bounds__(256) void ln_kernel(const float* __restrict__ in,
    const float* __restrict__ w, const float* __restrict__ b,
    __hip_bfloat16* __restrict__ out)
{
  __shared__ float sh[4];
  const int row = blockIdx.x;
  const float* xr = in + (size_t)row * DMODEL;
  float v[3]; float s = 0.f;
  #pragma unroll
  for (int i = 0; i < 3; i++){ int c = threadIdx.x + i*256; v[i] = xr[c]; s += v[i]; }
  s = block_sum256(s, sh);
  float mu = s * (1.f/DMODEL);
  float s2 = 0.f;
  #pragma unroll
  for (int i = 0; i < 3; i++){ float d = v[i]-mu; s2 += d*d; }
  s2 = block_sum256(s2, sh);
  float rs = rsqrtf(s2*(1.f/DMODEL) + EPSF);
  #pragma unroll
  for (int i = 0; i < 3; i++){
    int c = threadIdx.x + i*256;
    out[(size_t)row*DMODEL + c] = f2b((v[i]-mu)*rs*w[c] + b[c]);
  }
}

__device__ __forceinline__ s16x8 ld_frag(const ushort* p){
  union { ushort4 h[2]; s16x8 v; } u;
  u.h[0] = *(const ushort4*)(p);
  u.h[1] = *(const ushort4*)(p + 4);
  return u.v;
}

// ---- bf16 x bf16 MFMA GEMM, 64x64 tile, BK=64, dbuf(2), gload_lds w16 ----
// (r5-proven structure: one __syncthreads per K-step, 32KB LDS, 5 blocks/CU)
// EPI: 0 = plain store, 1 = bias + exact GELU. KS>1: per-slice partials.
template<typename CTy, int KS, int EPI>
__global__ __launch_bounds__(256) void gemm_bb64(const __hip_bfloat16* __restrict__ A_,
    const __hip_bfloat16* __restrict__ B_, CTy* __restrict__ C,
    const float* __restrict__ bias, int M, int N, int K)
{
  __shared__ __align__(16) ushort As[2][64][64];
  __shared__ __align__(16) ushort Bs[2][64][64];
  const int tid  = threadIdx.x;
  const int lane = tid & 63, wave = tid >> 6;
  const int wr = wave >> 1, wc = wave & 1;        // 2x2 wave grid
  const int n0 = blockIdx.x * 64, m0 = blockIdx.y * 64;
  const int Kc   = K / KS;
  const int kbeg = blockIdx.z * Kc;
  const int srw  = lane >> 3;                      // row-in-issue 0..7
  const int scol = (((lane & 7) ^ srw) << 3);      // swizzled src chunk (ushorts)
  const int l15  = lane & 15;
  const int r7   = l15 & 7;                        // frag row & 7 (i*16 preserves)
  const int c0   = lane >> 4;                      // frag chunk base 0..3

  const ushort* Au = (const ushort*)A_;
  const ushort* Bu = (const ushort*)B_;

  f32x4 acc[2][2] = {};

  auto stage = [&](int bf, int k0){
    #pragma unroll
    for (int q = 0; q < 2; q++){
      int row = q*32 + wave*8 + srw;
      gload16(Au + (size_t)(m0 + row)*K + kbeg + k0 + scol, &As[bf][q*32 + wave*8][0]);
      int nr = n0 + row; if (nr > N-1) nr = N-1;   // clamp; garbage cols never stored
      gload16(Bu + (size_t)nr*K + kbeg + k0 + scol, &Bs[bf][q*32 + wave*8][0]);
    }
  };

  stage(0, 0);
  __syncthreads();
  int cur = 0;
  for (int k0 = 0; k0 < Kc; k0 += 64){
    if (k0 + 64 < Kc) stage(cur ^ 1, k0 + 64);    // prefetch next K-tile
    #pragma unroll
    for (int t = 0; t < 2; t++){
      const int fc = (((t*4 + c0) ^ r7) << 3);    // swizzled frag col (ushorts)
      s16x8 a0 = ld_frag(&As[cur][wr*32      + l15][fc]);
      s16x8 a1 = ld_frag(&As[cur][wr*32 + 16 + l15][fc]);
      s16x8 b0 = ld_frag(&Bs[cur][wc*32      + l15][fc]);
      s16x8 b1 = ld_frag(&Bs[cur][wc*32 + 16 + l15][fc]);
      acc[0][0] = __builtin_amdgcn_mfma_f32_16x16x32_bf16(a0, b0, acc[0][0], 0, 0, 0);
      acc[0][1] = __builtin_amdgcn_mfma_f32_16x16x32_bf16(a0, b1, acc[0][1], 0, 0, 0);
      acc[1][0] = __builtin_amdgcn_mfma_f32_16x16x32_bf16(a1, b0, acc[1][0], 0, 0, 0);
      acc[1][1] = __builtin_amdgcn_mfma_f32_16x16x32_bf16(a1, b1, acc[1][1], 0, 0, 0);
    }
    __syncthreads();                               // drains vmcnt (next tile ready)
    cur ^= 1;
  }

  CTy* Cz = C + (size_t)blockIdx.z * M * N;
  // C/D layout (verified m89/m91): col = lane&15, row = (lane>>4)*4 + reg
  const int crow = (lane >> 4) * 4;
  #pragma unroll
  for (int i = 0; i < 2; i++){
    #pragma unroll
    for (int j = 0; j < 2; j++){
      int col = n0 + wc*32 + j*16 + l15;
      if (col < N){
        #pragma unroll
        for (int q = 0; q < 4; q++){
          int rowg = m0 + wr*32 + i*16 + crow + q;
          if constexpr (EPI == 1){
            float v = acc[i][j][q] + bias[col];
            Cz[(size_t)rowg*N + col] = (CTy)f2b(0.5f * v * (1.f + erff(v * 0.70710678118654752f)));
          } else if constexpr (sizeof(CTy) == 4){
            Cz[(size_t)rowg*N + col] = acc[i][j][q];
          } else {
            Cz[(size_t)rowg*N + col] = (CTy)f2b(acc[i][j][q]);
          }
        }
      }
    }
  }
}

// ---- fallback MFMA GEMM (fp32 B, 64x64 tile) -- used only if ws too small ----
template<typename CTy>
__global__ __launch_bounds__(256) void gemm_mfma(const __hip_bfloat16* __restrict__ A,
    const float* __restrict__ B, CTy* __restrict__ C, int M, int N, int K)
{
  __shared__ __align__(16) ushort As[64][72];
  __shared__ __align__(16) ushort Bs[64][72];
  const int tid  = threadIdx.x;
  const int lane = tid & 63, wave = tid >> 6;
  const int wr = wave >> 1, wc = wave & 1;
  const int n0 = blockIdx.x * 64, m0 = blockIdx.y * 64;
  const int sr = tid >> 2;
  const int sc = (tid & 3) * 16;
  const int l15 = lane & 15, lk = (lane >> 4) * 8;

  f32x4 acc[2][2] = {};

  const ushort* Au = (const ushort*)A;
  int nr = n0 + sr; if (nr > N-1) nr = N-1;

  for (int k0 = 0; k0 < K; k0 += 64){
    const ushort* ag = Au + (size_t)(m0 + sr)*K + (k0 + sc);
    ushort4 a0 = *(const ushort4*)(ag);
    ushort4 a1 = *(const ushort4*)(ag + 4);
    ushort4 a2 = *(const ushort4*)(ag + 8);
    ushort4 a3 = *(const ushort4*)(ag + 12);
    const float* bg = B + (size_t)nr*K + (k0 + sc);
    float4 f0 = *(const float4*)(bg);
    float4 f1 = *(const float4*)(bg + 4);
    float4 f2 = *(const float4*)(bg + 8);
    float4 f3 = *(const float4*)(bg + 12);
    ushort4 b0 = make_ushort4(f2bu(f0.x), f2bu(f0.y), f2bu(f0.z), f2bu(f0.w));
    ushort4 b1 = make_ushort4(f2bu(f1.x), f2bu(f1.y), f2bu(f1.z), f2bu(f1.w));
    ushort4 b2 = make_ushort4(f2bu(f2.x), f2bu(f2.y), f2bu(f2.z), f2bu(f2.w));
    ushort4 b3 = make_ushort4(f2bu(f3.x), f2bu(f3.y), f2bu(f3.z), f2bu(f3.w));

    __syncthreads();
    *(ushort4*)&As[sr][sc +  0] = a0;
    *(ushort4*)&As[sr][sc +  4] = a1;
    *(ushort4*)&As[sr][sc +  8] = a2;
    *(ushort4*)&As[sr][sc + 12] = a3;
    *(ushort4*)&Bs[sr][sc +  0] = b0;
    *(ushort4*)&Bs[sr][sc +  4] = b1;
    *(ushort4*)&Bs[sr][sc +  8] = b2;
    *(ushort4*)&Bs[sr][sc + 12] = b3;
    __syncthreads();

    #pragma unroll
    for (int kk = 0; kk < 64; kk += 32){
      s16x8 af0 = ld_frag(&As[wr*32      + l15][kk + lk]);
      s16x8 af1 = ld_frag(&As[wr*32 + 16 + l15][kk + lk]);
      s16x8 bf0 = ld_frag(&Bs[wc*32      + l15][kk + lk]);
      s16x8 bf1 = ld_frag(&Bs[wc*32 + 16 + l15][kk + lk]);
      acc[0][0] = __builtin_amdgcn_mfma_f32_16x16x32_bf16(af0, bf0, acc[0][0], 0, 0, 0);
      acc[0][1] = __builtin_amdgcn_mfma_f32_16x16x32_bf16(af0, bf1, acc[0][1], 0, 0, 0);
      acc[1][0] = __builtin_amdgcn_mfma_f32_16x16x32_bf16(af1, bf0, acc[1][0], 0, 0, 0);
      acc[1][1] = __builtin_amdgcn_mfma_f32_16x16x32_bf16(af1, bf1, acc[1][1], 0, 0, 0);
    }
  }

  const int crow = (lane >> 4) * 4;
  #pragma unroll
  for (int i = 0; i < 2; i++){
    #pragma unroll
    for (int j = 0; j < 2; j++){
      int col = n0 + wc*32 + j*16 + l15;
      if (col < N){
        #pragma unroll
        for (int q = 0; q < 4; q++){
          int rowg = m0 + wr*32 + i*16 + crow + q;
          if constexpr (sizeof(CTy) == 4) C[(size_t)rowg*N + col] = acc[i][j][q];
          else                            C[(size_t)rowg*N + col] = (CTy)f2b(acc[i][j][q]);
        }
      }
    }
  }
}

// ---- causal depthwise conv(4) + bias + silu (both dirs) + dt/dA prep ----
__global__ __launch_bounds__(256) void convdt_kernel(const __hip_bfloat16* __restrict__ zx,
    const float* __restrict__ cw, const float* __restrict__ cb,
    const float* __restrict__ dt_bias, const float* __restrict__ A_log,
    __hip_bfloat16* __restrict__ xconv, float* __restrict__ dtb, float* __restrict__ dab)
{
  const int tt = blockIdx.x, b = blockIdx.y, dir = blockIdx.z;
  const int c8 = threadIdx.x * 8;
  if (c8 < CONVDIM){
    size_t rowoff[4]; bool ok[4];
    #pragma unroll
    for (int k = 0; k < 4; k++){
      int s = tt - 3 + k;
      ok[k] = (s >= 0);
      int ss = ok[k] ? s : 0;
      int phys = dir ? (SEQ-1-ss) : ss;
      rowoff[k] = ((size_t)(b*SEQ + phys))*DINPROJ + DINNER + c8;
    }
    float acc[8];
    {
      float4 cb0 = *(const float4*)(cb + c8);
      float4 cb1 = *(const float4*)(cb + c8 + 4);
      acc[0]=cb0.x; acc[1]=cb0.y; acc[2]=cb0.z; acc[3]=cb0.w;
      acc[4]=cb1.x; acc[5]=cb1.y; acc[6]=cb1.z; acc[7]=cb1.w;
    }
    float wv[8][4];
    #pragma unroll
    for (int j = 0; j < 8; j++){
      float4 w4 = *(const float4*)(cw + (size_t)(c8 + j)*4);
      wv[j][0]=w4.x; wv[j][1]=w4.y; wv[j][2]=w4.z; wv[j][3]=w4.w;
    }
    const ushort* zu = (const ushort*)zx;
    #pragma unroll
    for (int k = 0; k < 4; k++){
      if (ok[k]){
        ushort4 v0 = *(const ushort4*)(zu + rowoff[k]);
        ushort4 v1 = *(const ushort4*)(zu + rowoff[k] + 4);
        acc[0] = fmaf(wv[0][k], u2f(v0.x), acc[0]);
        acc[1] = fmaf(wv[1][k], u2f(v0.y), acc[1]);
        acc[2] = fmaf(wv[2][k], u2f(v0.z), acc[2]);
        acc[3] = fmaf(wv[3][k], u2f(v0.w), acc[3]);
        acc[4] = fmaf(wv[4][k], u2f(v1.x), acc[4]);
        acc[5] = fmaf(wv[5][k], u2f(v1.y), acc[5]);
        acc[6] = fmaf(wv[6][k], u2f(v1.z), acc[6]);
        acc[7] = fmaf(wv[7][k], u2f(v1.w), acc[7]);
      }
    }
    ushort* outr = (ushort*)xconv + ((size_t)((dir*BSZ + b)*SEQ + tt))*CONVDIM + c8;
    ushort o[8];
    #pragma unroll
    for (int j = 0; j < 8; j++){
      float s = acc[j] / (1.f + expf(-acc[j]));   // silu
      o[j] = f2bu(s);
    }
    *(ushort4*)(outr)     = make_ushort4(o[0],o[1],o[2],o[3]);
    *(ushort4*)(outr + 4) = make_ushort4(o[4],o[5],o[6],o[7]);
  }
  if (dir == 0 && threadIdx.x < NHEADS){
    int h = threadIdx.x;
    size_t r = (size_t)b*SEQ + tt;
    float raw = b2f(zx[r*DINPROJ + (DINNER + CONVDIM) + h]) + dt_bias[h];
    float sp  = fmaxf(raw, 0.f) + log1pf(expf(-fabsf(raw)));   // stable softplus
    dtb[r*NHEADS + h] = sp;
    dab[r*NHEADS + h] = expf(-sp * expf(A_log[h]));
  }
}

// ======================= chunked selective scan =======================
#define CT 16

// pass1: local chunk scan, state update only. grid (NC-1, NHEADS, 4)
__global__ __launch_bounds__(256) void scan_pass1(const __hip_bfloat16* __restrict__ xconv,
    const float* __restrict__ dtb, const float* __restrict__ dab,
    float* __restrict__ stateBuf, int CL)
{
  const int c = blockIdx.x, h = blockIdx.y, z = blockIdx.z;
  const int b = z & 1, dir = z >> 1;
  const int tid = threadIdx.x, lane = tid & 63, wave = tid >> 6, nb = wave * 16;
  __shared__ __align__(16) float Bc[CT][64], Xc[CT][64];
  __shared__ float dAc[CT], dtc[CT];
  float hreg[16];
  #pragma unroll
  for (int j = 0; j < 16; j++) hreg[j] = 0.f;
  const size_t dirbase = (size_t)z * SEQ;
  const int cstart = c * CL;

  const int ttl = tid >> 4, c4 = (tid & 15) << 2;

  for (int c0 = cstart; c0 < cstart + CL; c0 += CT){
    {
      const ushort* rowp = (const ushort*)xconv + (dirbase + c0 + ttl)*(size_t)CONVDIM;
      ushort4 bv = *(const ushort4*)(rowp + DINNER + c4);
      ushort4 xv = *(const ushort4*)(rowp + h*HEADDIM + c4);
      Bc[ttl][c4+0] = u2f(bv.x); Bc[ttl][c4+1] = u2f(bv.y);
      Bc[ttl][c4+2] = u2f(bv.z); Bc[ttl][c4+3] = u2f(bv.w);
      Xc[ttl][c4+0] = u2f(xv.x); Xc[ttl][c4+1] = u2f(xv.y);
      Xc[ttl][c4+2] = u2f(xv.z); Xc[ttl][c4+3] = u2f(xv.w);
    }
    if (tid < CT){
      int phys = dir ? (SEQ-1 - (c0 + tid)) : (c0 + tid);
      size_t r = (size_t)b*SEQ + phys;
      dAc[tid] = dab[r*NHEADS + h];
      dtc[tid] = dtb[r*NHEADS + h];
    }
    __syncthreads();

    #pragma unroll 4
    for (int tt = 0; tt < CT; tt++){
      float dA = dAc[tt];
      float dtx = dtc[tt] * Xc[tt][lane];
      const float4* Bq = (const float4*)&Bc[tt][nb];
      float4 B0 = Bq[0], B1 = Bq[1], B2 = Bq[2], B3 = Bq[3];
      hreg[ 0]=fmaf(dA,hreg[ 0],dtx*B0.x); hreg[ 1]=fmaf(dA,hreg[ 1],dtx*B0.y);
      hreg[ 2]=fmaf(dA,hreg[ 2],dtx*B0.z); hreg[ 3]=fmaf(dA,hreg[ 3],dtx*B0.w);
      hreg[ 4]=fmaf(dA,hreg[ 4],dtx*B1.x); hreg[ 5]=fmaf(dA,hreg[ 5],dtx*B1.y);
      hreg[ 6]=fmaf(dA,hreg[ 6],dtx*B1.z); hreg[ 7]=fmaf(dA,hreg[ 7],dtx*B1.w);
      hreg[ 8]=fmaf(dA,hreg[ 8],dtx*B2.x); hreg[ 9]=fmaf(dA,hreg[ 9],dtx*B2.y);
      hreg[10]=fmaf(dA,hreg[10],dtx*B2.z); hreg[11]=fmaf(dA,hreg[11],dtx*B2.w);
      hreg[12]=fmaf(dA,hreg[12],dtx*B3.x); hreg[13]=fmaf(dA,hreg[13],dtx*B3.y);
      hreg[14]=fmaf(dA,hreg[14],dtx*B3.z); hreg[15]=fmaf(dA,hreg[15],dtx*B3.w);
    }
    __syncthreads();
  }

  float* sp = stateBuf + (((size_t)c*4 + z)*NHEADS + h)*4096 + (size_t)lane*64 + nb;
  *(float4*)(sp +  0) = make_float4(hreg[ 0],hreg[ 1],hreg[ 2],hreg[ 3]);
  *(float4*)(sp +  4) = make_float4(hreg[ 4],hreg[ 5],hreg[ 6],hreg[ 7]);
  *(float4*)(sp +  8) = make_float4(hreg[ 8],hreg[ 9],hreg[10],hreg[11]);
  *(float4*)(sp + 12) = make_float4(hreg[12],hreg[13],hreg[14],hreg[15]);
}

// fixup: h_init[c] = P_{c-1} h_init[c-1] + L_{c-1}; overwrites state[c] (c>=1).
// grid (NHEADS, 4)
__global__ __launch_bounds__(256) void scan_fixup(const float* __restrict__ dab,
    float* __restrict__ stateBuf, int NC, int CL)
{
  const int h = blockIdx.x, z = blockIdx.y;
  const int b = z & 1, dir = z >> 1;
  const int tid = threadIdx.x;
  __shared__ float sdA[SEQ];
  __shared__ float P[8];
  for (int i = tid; i < SEQ; i += 256){
    int phys = dir ? (SEQ-1-i) : i;
    sdA[i] = dab[((size_t)b*SEQ + phys)*NHEADS + h];
  }
  __syncthreads();
  if (tid < NC){
    float p = 1.f;
    for (int i = 0; i < CL; i++) p *= sdA[tid*CL + i];
    P[tid] = p;
  }
  __syncthreads();

  float hrun[16], Lcur[16];
  #pragma unroll
  for (int j = 0; j < 16; j++) hrun[j] = 0.f;
  {
    const float* s0 = stateBuf + ((size_t)z*NHEADS + h)*4096 + (size_t)tid*16;
    #pragma unroll
    for (int j = 0; j < 16; j++) Lcur[j] = s0[j];
  }
  for (int c = 1; c < NC; c++){
    float Pp = P[c-1];
    float hnew[16];
    #pragma unroll
    for (int j = 0; j < 16; j++) hnew[j] = fmaf(Pp, hrun[j], Lcur[j]);
    float* sc = stateBuf + (((size_t)c*4 + z)*NHEADS + h)*4096 + (size_t)tid*16;
    if (c < NC-1){
      #pragma unroll
      for (int j = 0; j < 16; j++) Lcur[j] = sc[j];   // read L_c before overwrite
    }
    #pragma unroll
    for (int j = 0; j < 16; j++) sc[j] = hnew[j];
    #pragma unroll
    for (int j = 0; j < 16; j++) hrun[j] = hnew[j];
  }
}

// pass2: full scan per chunk from h_init. grid (NC, NHEADS, 4)
__global__ __launch_bounds__(256) void scan_pass2(const __hip_bfloat16* __restrict__ xconv,
    const __hip_bfloat16* __restrict__ zx, const float* __restrict__ dtb,
    const float* __restrict__ dab, const float* __restrict__ Dp,
    const float* __restrict__ stateBuf, __hip_bfloat16* __restrict__ yg, int CL)
{
  const int c = blockIdx.x, h = blockIdx.y, z = blockIdx.z;
  const int b = z & 1, dir = z >> 1;
  const int tid = threadIdx.x, lane = tid & 63, wave = tid >> 6, nb = wave * 16;
  __shared__ __align__(16) float Bc[CT][64], Cc[CT][64], Xc[CT][64];
  __shared__ __align__(16) float Yp[4][CT][64];
  __shared__ float dAc[CT], dtc[CT];
  float hreg[16];
  if (c == 0){
    #pragma unroll
    for (int j = 0; j < 16; j++) hreg[j] = 0.f;
  } else {
    const float* sp = stateBuf + (((size_t)c*4 + z)*NHEADS + h)*4096 + (size_t)lane*64 + nb;
    float4 s0 = *(const float4*)(sp+0), s1 = *(const float4*)(sp+4);
    float4 s2 = *(const float4*)(sp+8), s3 = *(const float4*)(sp+12);
    hreg[ 0]=s0.x; hreg[ 1]=s0.y; hreg[ 2]=s0.z; hreg[ 3]=s0.w;
    hreg[ 4]=s1.x; hreg[ 5]=s1.y; hreg[ 6]=s1.z; hreg[ 7]=s1.w;
    hreg[ 8]=s2.x; hreg[ 9]=s2.y; hreg[10]=s2.z; hreg[11]=s2.w;
    hreg[12]=s3.x; hreg[13]=s3.y; hreg[14]=s3.z; hreg[15]=s3.w;
  }
  const float Dh = Dp[h];
  const size_t dirbase = (size_t)z * SEQ;
  const int cstart = c * CL;
  const int ttl = tid >> 4, c4 = (tid & 15) << 2;

  for (int c0 = cstart; c0 < cstart + CL; c0 += CT){
    {
      const ushort* rowp = (const ushort*)xconv + (dirbase + c0 + ttl)*(size_t)CONVDIM;
      ushort4 bv = *(const ushort4*)(rowp + DINNER + c4);
      ushort4 cv = *(const ushort4*)(rowp + DINNER + DSTATE + c4);
      ushort4 xv = *(const ushort4*)(rowp + h*HEADDIM + c4);
      Bc[ttl][c4+0] = u2f(bv.x); Bc[ttl][c4+1] = u2f(bv.y);
      Bc[ttl][c4+2] = u2f(bv.z); Bc[ttl][c4+3] = u2f(bv.w);
      Cc[ttl][c4+0] = u2f(cv.x); Cc[ttl][c4+1] = u2f(cv.y);
      Cc[ttl][c4+2] = u2f(cv.z); Cc[ttl][c4+3] = u2f(cv.w);
      Xc[ttl][c4+0] = u2f(xv.x); Xc[ttl][c4+1] = u2f(xv.y);
      Xc[ttl][c4+2] = u2f(xv.z); Xc[ttl][c4+3] = u2f(xv.w);
    }
    if (tid < CT){
      int phys = dir ? (SEQ-1 - (c0 + tid)) : (c0 + tid);
      size_t r = (size_t)b*SEQ + phys;
      dAc[tid] = dab[r*NHEADS + h];
      dtc[tid] = dtb[r*NHEADS + h];
    }
    __syncthreads();

    #pragma unroll 4
    for (int tt = 0; tt < CT; tt++){
      float dA = dAc[tt];
      float dtx = dtc[tt] * Xc[tt][lane];
      const float4* Bq = (const float4*)&Bc[tt][nb];
      const float4* Cq = (const float4*)&Cc[tt][nb];
      float4 B0 = Bq[0], B1 = Bq[1], B2 = Bq[2], B3 = Bq[3];
      float4 C0 = Cq[0], C1 = Cq[1], C2 = Cq[2], C3 = Cq[3];
      float y0 = 0.f, y1 = 0.f, y2 = 0.f, y3 = 0.f;
      hreg[ 0]=fmaf(dA,hreg[ 0],dtx*B0.x); y0=fmaf(hreg[ 0],C0.x,y0);
      hreg[ 1]=fmaf(dA,hreg[ 1],dtx*B0.y); y1=fmaf(hreg[ 1],C0.y,y1);
      hreg[ 2]=fmaf(dA,hreg[ 2],dtx*B0.z); y2=fmaf(hreg[ 2],C0.z,y2);
      hreg[ 3]=fmaf(dA,hreg[ 3],dtx*B0.w); y3=fmaf(hreg[ 3],C0.w,y3);
      hreg[ 4]=fmaf(dA,hreg[ 4],dtx*B1.x); y0=fmaf(hreg[ 4],C1.x,y0);
      hreg[ 5]=fmaf(dA,hreg[ 5],dtx*B1.y); y1=fmaf(hreg[ 5],C1.y,y1);
      hreg[ 6]=fmaf(dA,hreg[ 6],dtx*B1.z); y2=fmaf(hreg[ 6],C1.z,y2);
      hreg[ 7]=fmaf(dA,hreg[ 7],dtx*B1.w); y3=fmaf(hreg[ 7],C1.w,y3);
      hreg[ 8]=fmaf(dA,hreg[ 8],dtx*B2.x); y0=fmaf(hreg[ 8],C2.x,y0);
      hreg[ 9]=fmaf(dA,hreg[ 9],dtx*B2.y); y1=fmaf(hreg[ 9],C2.y,y1);
      hreg[10]=fmaf(dA,hreg[10],dtx*B2.z); y2=fmaf(hreg[10],C2.z,y2);
      hreg[11]=fmaf(dA,hreg[11],dtx*B2.w); y3=fmaf(hreg[11],C2.w,y3);
      hreg[12]=fmaf(dA,hreg[12],dtx*B3.x); y0=fmaf(hreg[12],C3.x,y0);
      hreg[13]=fmaf(dA,hreg[13],dtx*B3.y); y1=fmaf(hreg[13],C3.y,y1);
      hreg[14]=fmaf(dA,hreg[14],dtx*B3.z); y2=fmaf(hreg[14],C3.z,y2);
      hreg[15]=fmaf(dA,hreg[15],dtx*B3.w); y3=fmaf(hreg[15],C3.w,y3);
      Yp[wave][tt][lane] = (y0+y1) + (y2+y3);
    }
    __syncthreads();

    {
      // vectorized epilogue: 4 consecutive p per thread
      int tl = tid >> 4, p4 = (tid & 15) << 2;
      float4 ya = *(const float4*)&Yp[0][tl][p4];
      float4 yb4 = *(const float4*)&Yp[1][tl][p4];
      float4 yc = *(const float4*)&Yp[2][tl][p4];
      float4 yd = *(const float4*)&Yp[3][tl][p4];
      float4 xv = *(const float4*)&Xc[tl][p4];
      int phys = dir ? (SEQ-1 - (c0 + tl)) : (c0 + tl);
      size_t r = (size_t)b*SEQ + phys;
      const ushort* zp = (const ushort*)zx + r*DINPROJ + h*HEADDIM + p4;
      ushort4 zv = *(const ushort4*)zp;
      float zf[4] = { u2f(zv.x), u2f(zv.y), u2f(zv.z), u2f(zv.w) };
      float yv[4] = { ya.x+yb4.x+yc.x+yd.x + Dh*xv.x,
                      ya.y+yb4.y+yc.y+yd.y + Dh*xv.y,
                      ya.z+yb4.z+yc.z+yd.z + Dh*xv.z,
                      ya.w+yb4.w+yc.w+yd.w + Dh*xv.w };
      ushort o[4];
      #pragma unroll
      for (int j = 0; j < 4; j++){
        float sil = zf[j] / (1.f + expf(-zf[j]));
        o[j] = f2bu(yv[j] * sil);
      }
      ushort* op = (ushort*)yg + ((size_t)dir*ROWS + r)*DINNER + h*HEADDIM + p4;
      *(ushort4*)op = make_ushort4(o[0],o[1],o[2],o[3]);
    }
    __syncthreads();
  }
}

// ---- per-row gated RMSNorm both dirs + combine (fp32 norm_w) -> u bf16 ----
__global__ __launch_bounds__(256) void rmscomb_kernel(const __hip_bfloat16* __restrict__ yg,
    const float* __restrict__ nw, __hip_bfloat16* __restrict__ u)
{
  __shared__ float sh[4];
  const int row = blockIdx.x;
  const __hip_bfloat16* yf = yg + (size_t)row*DINNER;
  const __hip_bfloat16* yb = yg + (size_t)(ROWS + row)*DINNER;
  float vf[6], vb[6]; float sf = 0.f, sb = 0.f;
  #pragma unroll
  for (int i = 0; i < 6; i++){
    int c = threadIdx.x + i*256;
    vf[i] = b2f(yf[c]); sf += vf[i]*vf[i];
    vb[i] = b2f(yb[c]); sb += vb[i]*vb[i];
  }
  sf = block_sum256(sf, sh);
  sb = block_sum256(sb, sh);
  float rf = rsqrtf(sf*(1.f/DINNER) + EPSF);
  float rb = rsqrtf(sb*(1.f/DINNER) + EPSF);
  #pragma unroll
  for (int i = 0; i < 6; i++){
    int c = threadIdx.x + i*256;
    u[(size_t)row*DINNER + c] = f2b((vf[i]*rf + vb[i]*rb) * nw[c]);
  }
}

// ---- ln2 on NP fp32 partials -> bf16 mb ----
template<int NP>
__global__ __launch_bounds__(256) void ln2_kernel(const float* __restrict__ in,
    size_t pstride, const float* __restrict__ w, const float* __restrict__ b,
    __hip_bfloat16* __restrict__ out)
{
  __shared__ float sh[4];
  const int row = blockIdx.x;
  float v[3]; float s = 0.f;
  #pragma unroll
  for (int i = 0; i < 3; i++){
    int c = threadIdx.x + i*256;
    size_t idx = (size_t)row*DMODEL + c;
    float t = 0.f;
    #pragma unroll
    for (int p = 0; p < NP; p++) t += in[p*pstride + idx];
    v[i] = t; s += t;
  }
  s = block_sum256(s, sh);
  float mu = s * (1.f/DMODEL);
  float s2 = 0.f;
  #pragma unroll
  for (int i = 0; i < 3; i++){ float d = v[i]-mu; s2 += d*d; }
  s2 = block_sum256(s2, sh);
  float rs = rsqrtf(s2*(1.f/DMODEL) + EPSF);
  #pragma unroll
  for (int i = 0; i < 3; i++){
    int c = threadIdx.x + i*256;
    out[(size_t)row*DMODEL + c] = f2b((v[i]-mu)*rs*w[c] + b[c]);
  }
}

// ---- exact GELU with fp32 bias (fallback path only) ----
__global__ __launch_bounds__(256) void gelu_kernel(const __hip_bfloat16* __restrict__ g,
    const float* __restrict__ b1, __hip_bfloat16* __restrict__ out)
{
  size_t idx = (size_t)blockIdx.x*256 + threadIdx.x;
  int c = (int)(idx % DFF);
  float v = b2f(g[idx]) + b1[c];
  out[idx] = f2b(0.5f * v * (1.f + erff(v * 0.70710678118654752f)));
}

// ---- final: sum NP fp32 partials + bias + residual -> fp32 out (x4 vec) ----
template<int NP>
__global__ __launch_bounds__(256) void final_kernel(const float* __restrict__ f,
    size_t pstride, const float* __restrict__ bias, const float* __restrict__ x,
    float* __restrict__ out)
{
  size_t i4 = ((size_t)blockIdx.x*256 + threadIdx.x) << 2;
  int c = (int)(i4 % DMODEL);
  float4 bv = *(const float4*)(bias + c);
  float4 xv = *(const float4*)(x + i4);
  float4 s = make_float4(bv.x+xv.x, bv.y+xv.y, bv.z+xv.z, bv.w+xv.w);
  #pragma unroll
  for (int p = 0; p < NP; p++){
    float4 fv = *(const float4*)(f + p*pstride + i4);
    s.x += fv.x; s.y += fv.y; s.z += fv.z; s.w += fv.w;
  }
  *(float4*)(out + i4) = s;
}

extern "C" void kernel_launch(void* const* d_in, const int* in_sizes, int n_in,
                              void* d_out, int out_size, void* d_ws, size_t ws_size,
                              hipStream_t stream)
{
  float* out = (float*)d_out;

  const size_t NEED = 19906560;   // base plan (proven to fit)
  if (ws_size < NEED || n_in < 17){
    zerof_kernel<<<(out_size + 255)/256, 256, 0, stream>>>(out, out_size);
    return;
  }

  const float* x       = (const float*)d_in[0];
  const float* in_proj_w = (const float*)d_in[1];
  const float* conv_w  = (const float*)d_in[2];
  const float* conv_b  = (const float*)d_in[3];
  const float* dt_bias = (const float*)d_in[4];
  const float* A_log   = (const float*)d_in[5];
  const float* D_param = (const float*)d_in[6];
  const float* norm_w  = (const float*)d_in[7];
  const float* out_proj_w = (const float*)d_in[8];
  const float* ln1_w   = (const float*)d_in[9];
  const float* ln1_b   = (const float*)d_in[10];
  const float* ln2_w   = (const float*)d_in[11];
  const float* ln2_b   = (const float*)d_in[12];
  const float* ff_w1   = (const float*)d_in[13];
  const float* ff_b1   = (const float*)d_in[14];
  const float* ff_w2   = (const float*)d_in[15];
  const float* ff_b2   = (const float*)d_in[16];

  char* ws = (char*)d_ws;
  __hip_bfloat16* zx  = (__hip_bfloat16*)(ws + 0);         // 6,602,752
  __hip_bfloat16* xn  = (__hip_bfloat16*)(ws + 6602752);   // 1,572,864 (dead after s2)
  float*          dtb = (float*)(ws + 6602752);            //    98,304 (over xn)
  float*          dab = (float*)(ws + 6701056);            //    98,304
  __hip_bfloat16* xcv = (__hip_bfloat16*)(ws + 6799360);   // 6,815,744 -> 13,615,104
  __hip_bfloat16* yg  = (__hip_bfloat16*)(ws + 13615104);  // 6,291,456 -> 19,906,560
  __hip_bfloat16* u   = (__hip_bfloat16*)(ws + 0);         // over zx (dead after scan)
  float*          mo  = (float*)(ws + 3145728);            // over zx (fallback)
  __hip_bfloat16* mb  = (__hip_bfloat16*)(ws + 0);         // over u (dead)
  __hip_bfloat16* g   = (__hip_bfloat16*)(ws + 6799360);   // over xcv (fallback)
  __hip_bfloat16* gb  = (__hip_bfloat16*)(ws + 13615104);  // over yg (dead)
  float*          fo  = (float*)(ws + 0);                  // over mb (fallback)

  // fast-path extra regions beyond base plan (ws observed ~268 MB):
  const size_t WBALL = 16748544;        // all 4 weight matrices bf16
  const size_t PARTS = 12582912;        // 4 fp32 partials of ROWS*DMODEL
  const size_t CHB   = 1572864;         // per-chunk scan states
  const size_t PSTRIDE = (size_t)ROWS * DMODEL;
  const int WN_IN  = DINPROJ*DMODEL;    // 2,476,032
  const int WN_OUT = DMODEL*DINNER;     // 1,179,648
  const int WN_F1  = DFF*DMODEL;        // 2,359,296
  const int WN_F2  = DMODEL*DFF;        // 2,359,296

  size_t rem = ws_size - NEED;
  bool fast = (rem >= WBALL + PARTS);
  ushort* wb    = (ushort*)(ws + NEED);
  float*  parts = (float*) (ws + NEED + WBALL);
  size_t scanoff = NEED + (fast ? (WBALL + PARTS) : 0);
  size_t srem = ws_size - scanoff;
  int NC = 1;
  if      (srem >= 8*CHB) NC = 8;
  else if (srem >= 4*CHB) NC = 4;
  else if (srem >= 2*CHB) NC = 2;
  float* stateBuf = (float*)(ws + scanoff);
  const int CL = SEQ / NC;

  if (fast){
    // 1+2) fused: weight conversion (all 4) + ln1
    const int wblocks = (WN_IN + WN_OUT + WN_F1 + WN_F2) / 4 / 256;   // 8178 exact
    prep_kernel<<<wblocks + ROWS, 256, 0, stream>>>(in_proj_w, out_proj_w, ff_w1, ff_w2,
        wb, WN_IN, WN_OUT, WN_F1, WN_F2, wblocks, x, ln1_w, ln1_b, xn);
    // 3) in_proj -> zx bf16
    gemm_bb64<__hip_bfloat16,1,0><<<dim3((DINPROJ+63)/64, ROWS/64), 256, 0, stream>>>(
        xn, (const __hip_bfloat16*)wb, zx, nullptr, ROWS, DINPROJ, DMODEL);
  } else {
    ln_kernel<<<ROWS, 256, 0, stream>>>(x, ln1_w, ln1_b, xn);
    gemm_mfma<<<dim3((DINPROJ+63)/64, ROWS/64), 256, 0, stream>>>(xn, in_proj_w, zx, ROWS, DINPROJ, DMODEL);
  }
  // 4) conv + silu + dt/dA
  convdt_kernel<<<dim3(SEQ, BSZ, 2), 256, 0, stream>>>(zx, conv_w, conv_b, dt_bias, A_log, xcv, dtb, dab);
  // 5) chunked scan (separate tiny fixup kernel; pass2 reads one state)
  if (NC > 1){
    scan_pass1<<<dim3(NC-1, NHEADS, 4), 256, 0, stream>>>(xcv, dtb, dab, stateBuf, CL);
    scan_fixup<<<dim3(NHEADS, 4), 256, 0, stream>>>(dab, stateBuf, NC, CL);
  }
  scan_pass2<<<dim3(NC, NHEADS, 4), 256, 0, stream>>>(xcv, zx, dtb, dab, D_param, stateBuf, yg, CL);
  // 6) per-dir RMS + combine -> u
  rmscomb_kernel<<<ROWS, 256, 0, stream>>>(yg, norm_w, u);
  // 7) out_proj [split-K=2, partials] ; 8) ln2 sums partials
  if (fast){
    gemm_bb64<float,2,0><<<dim3(DMODEL/64, ROWS/64, 2), 256, 0, stream>>>(
        u, (const __hip_bfloat16*)(wb + WN_IN), parts, nullptr, ROWS, DMODEL, DINNER);
    ln2_kernel<2><<<ROWS, 256, 0, stream>>>(parts, PSTRIDE, ln2_w, ln2_b, mb);
  } else {
    gemm_mfma<<<dim3(DMODEL/64, ROWS/64), 256, 0, stream>>>(u, out_proj_w, mo, ROWS, DMODEL, DINNER);
    ln2_kernel<1><<<ROWS, 256, 0, stream>>>(mo, 0, ln2_w, ln2_b, mb);
  }
  // 9) ff1 (+bias+gelu fused) -> gb
  if (fast){
    gemm_bb64<__hip_bfloat16,1,1><<<dim3(DFF/64, ROWS/64), 256, 0, stream>>>(
        mb, (const __hip_bfloat16*)(wb + WN_IN + WN_OUT), gb, ff_b1, ROWS, DFF, DMODEL);
  } else {
    gemm_mfma<<<dim3(DFF/64, ROWS/64), 256, 0, stream>>>(mb, ff_w1, g, ROWS, DFF, DMODEL);
    gelu_kernel<<<(ROWS*DFF)/256, 256, 0, stream>>>(g, ff_b1, gb);
  }
  // 10) ff2 [split-K=4, partials] ; 11) final sums + bias + residual
  if (fast){
    gemm_bb64<float,4,0><<<dim3(DMODEL/64, ROWS/64, 4), 256, 0, stream>>>(
        gb, (const __hip_bfloat16*)(wb + WN_IN + WN_OUT + WN_F1), parts, nullptr, ROWS, DMODEL, DFF);
    final_kernel<4><<<(ROWS*DMODEL/4)/256, 256, 0, stream>>>(parts, PSTRIDE, ff_b2, x, out);
  } else {
    gemm_mfma<<<dim3(DMODEL/64, ROWS/64), 256, 0, stream>>>(gb, ff_w2, fo, ROWS, DMODEL, DFF);
    final_kernel<1><<<(ROWS*DMODEL/4)/256, 256, 0, stream>>>(fo, 0, ff_b2, x, out);
  }
}

// Round 9
// 243.447 us; speedup vs baseline: 1.1047x; 1.0288x over previous
//
#include <hip/hip_runtime.h>
#include <hip/hip_bf16.h>
#include <math.h>

#define SEQ     512
#define BSZ     2
#define ROWS    (BSZ*SEQ)      // 1024
#define DMODEL  768
#define DINNER  1536
#define DSTATE  64
#define NHEADS  24
#define HEADDIM 64
#define CONVDIM 1664
#define DINPROJ 3224
#define DFF     3072
#define EPSF    1e-5f

typedef __attribute__((ext_vector_type(8))) short s16x8;   // 8 bf16 = 4 VGPRs
typedef __attribute__((ext_vector_type(4))) float f32x4;   // MFMA accumulator

__device__ __forceinline__ float b2f(const __hip_bfloat16 v){ return __bfloat162float(v); }
__device__ __forceinline__ __hip_bfloat16 f2b(float v){ return __float2bfloat16(v); }
__device__ __forceinline__ ushort f2bu(float v){
  union { __hip_bfloat16 b; ushort u; } c; c.b = __float2bfloat16(v); return c.u;
}
__device__ __forceinline__ float u2f(ushort u){ return __uint_as_float(((uint)u) << 16); }

// async global->LDS, 16B per lane; LDS dest = wave-uniform base + lane*16
__device__ __forceinline__ void gload16(const void* g, void* l){
  __builtin_amdgcn_global_load_lds((__attribute__((address_space(1))) const void*)g,
                                   (__attribute__((address_space(3))) void*)l, 16, 0, 0);
}

__device__ __forceinline__ float block_sum256(float v, float* sh){
  #pragma unroll
  for (int off = 32; off > 0; off >>= 1) v += __shfl_down(v, off, 64);
  int w = threadIdx.x >> 6;
  if ((threadIdx.x & 63) == 0) sh[w] = v;
  __syncthreads();
  float t = sh[0] + sh[1] + sh[2] + sh[3];
  __syncthreads();
  return t;
}

__global__ __launch_bounds__(256) void zerof_kernel(float* out, int n){
  int i = blockIdx.x*256 + threadIdx.x;
  if (i < n) out[i] = 0.f;
}

// ---- fused prep: [blocks < wblocks] all-weights fp32->bf16 ; [rest] ln1 ----
__global__ __launch_bounds__(256) void prep_kernel(const float* __restrict__ w0,
    const float* __restrict__ w1, const float* __restrict__ w2,
    const float* __restrict__ w3, ushort* __restrict__ o,
    int n0, int n1, int n2, int n3, int wblocks,
    const float* __restrict__ xin, const float* __restrict__ lnw,
    const float* __restrict__ lnb, __hip_bfloat16* __restrict__ xnout)
{
  __shared__ float sh[4];
  if ((int)blockIdx.x < wblocks){
    int i = (blockIdx.x*256 + threadIdx.x) << 2;
    int total = n0 + n1 + n2 + n3;
    if (i < total){
      const float* s; int off;
      if      (i < n0)       { s = w0; off = i; }
      else if (i < n0+n1)    { s = w1; off = i - n0; }
      else if (i < n0+n1+n2) { s = w2; off = i - n0 - n1; }
      else                   { s = w3; off = i - n0 - n1 - n2; }
      float4 f = *(const float4*)(s + off);
      *(ushort4*)(o + i) = make_ushort4(f2bu(f.x), f2bu(f.y), f2bu(f.z), f2bu(f.w));
    }
    return;
  }
  const int row = blockIdx.x - wblocks;
  const float* xr = xin + (size_t)row * DMODEL;
  float v[3]; float s = 0.f;
  #pragma unroll
  for (int i = 0; i < 3; i++){ int c = threadIdx.x + i*256; v[i] = xr[c]; s += v[i]; }
  s = block_sum256(s, sh);
  float mu = s * (1.f/DMODEL);
  float s2 = 0.f;
  #pragma unroll
  for (int i = 0; i < 3; i++){ float d = v[i]-mu; s2 += d*d; }
  s2 = block_sum256(s2, sh);
  float rs = rsqrtf(s2*(1.f/DMODEL) + EPSF);
  #pragma unroll
  for (int i = 0; i < 3; i++){
    int c = threadIdx.x + i*256;
    xnout[(size_t)row*DMODEL + c] = f2b((v[i]-mu)*rs*lnw[c] + lnb[c]);
  }
}

// ---- LayerNorm (fallback path) ----
__global__ __launch_bounds__(256) void ln_kernel(const float* __restrict__ in,
    const float* __restrict__ w, const float* __restrict__ b,
    __hip_bfloat16* __restrict__ out)
{
  __shared__ float sh[4];
  const int row = blockIdx.x;
  const float* xr = in + (size_t)row * DMODEL;
  float v[3]; float s = 0.f;
  #pragma unroll
  for (int i = 0; i < 3; i++){ int c = threadIdx.x + i*256; v[i] = xr[c]; s += v[i]; }
  s = block_sum256(s, sh);
  float mu = s * (1.f/DMODEL);
  float s2 = 0.f;
  #pragma unroll
  for (int i = 0; i < 3; i++){ float d = v[i]-mu; s2 += d*d; }
  s2 = block_sum256(s2, sh);
  float rs = rsqrtf(s2*(1.f/DMODEL) + EPSF);
  #pragma unroll
  for (int i = 0; i < 3; i++){
    int c = threadIdx.x + i*256;
    out[(size_t)row*DMODEL + c] = f2b((v[i]-mu)*rs*w[c] + b[c]);
  }
}

__device__ __forceinline__ s16x8 ld_frag(const ushort* p){
  union { ushort4 h[2]; s16x8 v; } u;
  u.h[0] = *(const ushort4*)(p);
  u.h[1] = *(const ushort4*)(p + 4);
  return u.v;
}

// ---- bf16 x bf16 MFMA GEMM, 64x64 tile, BK=64, dbuf(2), gload_lds w16 ----
// (r5-proven structure: one __syncthreads per K-step, 32KB LDS, 5 blocks/CU)
// EPI: 0 = plain store, 1 = bias + exact GELU. KS>1: per-slice partials.
template<typename CTy, int KS, int EPI>
__global__ __launch_bounds__(256) void gemm_bb64(const __hip_bfloat16* __restrict__ A_,
    const __hip_bfloat16* __restrict__ B_, CTy* __restrict__ C,
    const float* __restrict__ bias, int M, int N, int K)
{
  __shared__ __align__(16) ushort As[2][64][64];
  __shared__ __align__(16) ushort Bs[2][64][64];
  const int tid  = threadIdx.x;
  const int lane = tid & 63, wave = tid >> 6;
  const int wr = wave >> 1, wc = wave & 1;        // 2x2 wave grid
  const int n0 = blockIdx.x * 64, m0 = blockIdx.y * 64;
  const int Kc   = K / KS;
  const int kbeg = blockIdx.z * Kc;
  const int srw  = lane >> 3;                      // row-in-issue 0..7
  const int scol = (((lane & 7) ^ srw) << 3);      // swizzled src chunk (ushorts)
  const int l15  = lane & 15;
  const int r7   = l15 & 7;                        // frag row & 7 (i*16 preserves)
  const int c0   = lane >> 4;                      // frag chunk base 0..3

  const ushort* Au = (const ushort*)A_;
  const ushort* Bu = (const ushort*)B_;

  f32x4 acc[2][2] = {};

  auto stage = [&](int bf, int k0){
    #pragma unroll
    for (int q = 0; q < 2; q++){
      int row = q*32 + wave*8 + srw;
      gload16(Au + (size_t)(m0 + row)*K + kbeg + k0 + scol, &As[bf][q*32 + wave*8][0]);
      int nr = n0 + row; if (nr > N-1) nr = N-1;   // clamp; garbage cols never stored
      gload16(Bu + (size_t)nr*K + kbeg + k0 + scol, &Bs[bf][q*32 + wave*8][0]);
    }
  };

  stage(0, 0);
  __syncthreads();
  int cur = 0;
  for (int k0 = 0; k0 < Kc; k0 += 64){
    if (k0 + 64 < Kc) stage(cur ^ 1, k0 + 64);    // prefetch next K-tile
    #pragma unroll
    for (int t = 0; t < 2; t++){
      const int fc = (((t*4 + c0) ^ r7) << 3);    // swizzled frag col (ushorts)
      s16x8 a0 = ld_frag(&As[cur][wr*32      + l15][fc]);
      s16x8 a1 = ld_frag(&As[cur][wr*32 + 16 + l15][fc]);
      s16x8 b0 = ld_frag(&Bs[cur][wc*32      + l15][fc]);
      s16x8 b1 = ld_frag(&Bs[cur][wc*32 + 16 + l15][fc]);
      acc[0][0] = __builtin_amdgcn_mfma_f32_16x16x32_bf16(a0, b0, acc[0][0], 0, 0, 0);
      acc[0][1] = __builtin_amdgcn_mfma_f32_16x16x32_bf16(a0, b1, acc[0][1], 0, 0, 0);
      acc[1][0] = __builtin_amdgcn_mfma_f32_16x16x32_bf16(a1, b0, acc[1][0], 0, 0, 0);
      acc[1][1] = __builtin_amdgcn_mfma_f32_16x16x32_bf16(a1, b1, acc[1][1], 0, 0, 0);
    }
    __syncthreads();                               // drains vmcnt (next tile ready)
    cur ^= 1;
  }

  CTy* Cz = C + (size_t)blockIdx.z * M * N;
  // C/D layout (verified m89/m91): col = lane&15, row = (lane>>4)*4 + reg
  const int crow = (lane >> 4) * 4;
  #pragma unroll
  for (int i = 0; i < 2; i++){
    #pragma unroll
    for (int j = 0; j < 2; j++){
      int col = n0 + wc*32 + j*16 + l15;
      if (col < N){
        #pragma unroll
        for (int q = 0; q < 4; q++){
          int rowg = m0 + wr*32 + i*16 + crow + q;
          if constexpr (EPI == 1){
            float v = acc[i][j][q] + bias[col];
            Cz[(size_t)rowg*N + col] = (CTy)f2b(0.5f * v * (1.f + erff(v * 0.70710678118654752f)));
          } else if constexpr (sizeof(CTy) == 4){
            Cz[(size_t)rowg*N + col] = acc[i][j][q];
          } else {
            Cz[(size_t)rowg*N + col] = (CTy)f2b(acc[i][j][q]);
          }
        }
      }
    }
  }
}

// ---- fallback MFMA GEMM (fp32 B, 64x64 tile) -- used only if ws too small ----
template<typename CTy>
__global__ __launch_bounds__(256) void gemm_mfma(const __hip_bfloat16* __restrict__ A,
    const float* __restrict__ B, CTy* __restrict__ C, int M, int N, int K)
{
  __shared__ __align__(16) ushort As[64][72];
  __shared__ __align__(16) ushort Bs[64][72];
  const int tid  = threadIdx.x;
  const int lane = tid & 63, wave = tid >> 6;
  const int wr = wave >> 1, wc = wave & 1;
  const int n0 = blockIdx.x * 64, m0 = blockIdx.y * 64;
  const int sr = tid >> 2;
  const int sc = (tid & 3) * 16;
  const int l15 = lane & 15, lk = (lane >> 4) * 8;

  f32x4 acc[2][2] = {};

  const ushort* Au = (const ushort*)A;
  int nr = n0 + sr; if (nr > N-1) nr = N-1;

  for (int k0 = 0; k0 < K; k0 += 64){
    const ushort* ag = Au + (size_t)(m0 + sr)*K + (k0 + sc);
    ushort4 a0 = *(const ushort4*)(ag);
    ushort4 a1 = *(const ushort4*)(ag + 4);
    ushort4 a2 = *(const ushort4*)(ag + 8);
    ushort4 a3 = *(const ushort4*)(ag + 12);
    const float* bg = B + (size_t)nr*K + (k0 + sc);
    float4 f0 = *(const float4*)(bg);
    float4 f1 = *(const float4*)(bg + 4);
    float4 f2 = *(const float4*)(bg + 8);
    float4 f3 = *(const float4*)(bg + 12);
    ushort4 b0 = make_ushort4(f2bu(f0.x), f2bu(f0.y), f2bu(f0.z), f2bu(f0.w));
    ushort4 b1 = make_ushort4(f2bu(f1.x), f2bu(f1.y), f2bu(f1.z), f2bu(f1.w));
    ushort4 b2 = make_ushort4(f2bu(f2.x), f2bu(f2.y), f2bu(f2.z), f2bu(f2.w));
    ushort4 b3 = make_ushort4(f2bu(f3.x), f2bu(f3.y), f2bu(f3.z), f2bu(f3.w));

    __syncthreads();
    *(ushort4*)&As[sr][sc +  0] = a0;
    *(ushort4*)&As[sr][sc +  4] = a1;
    *(ushort4*)&As[sr][sc +  8] = a2;
    *(ushort4*)&As[sr][sc + 12] = a3;
    *(ushort4*)&Bs[sr][sc +  0] = b0;
    *(ushort4*)&Bs[sr][sc +  4] = b1;
    *(ushort4*)&Bs[sr][sc +  8] = b2;
    *(ushort4*)&Bs[sr][sc + 12] = b3;
    __syncthreads();

    #pragma unroll
    for (int kk = 0; kk < 64; kk += 32){
      s16x8 af0 = ld_frag(&As[wr*32      + l15][kk + lk]);
      s16x8 af1 = ld_frag(&As[wr*32 + 16 + l15][kk + lk]);
      s16x8 bf0 = ld_frag(&Bs[wc*32      + l15][kk + lk]);
      s16x8 bf1 = ld_frag(&Bs[wc*32 + 16 + l15][kk + lk]);
      acc[0][0] = __builtin_amdgcn_mfma_f32_16x16x32_bf16(af0, bf0, acc[0][0], 0, 0, 0);
      acc[0][1] = __builtin_amdgcn_mfma_f32_16x16x32_bf16(af0, bf1, acc[0][1], 0, 0, 0);
      acc[1][0] = __builtin_amdgcn_mfma_f32_16x16x32_bf16(af1, bf0, acc[1][0], 0, 0, 0);
      acc[1][1] = __builtin_amdgcn_mfma_f32_16x16x32_bf16(af1, bf1, acc[1][1], 0, 0, 0);
    }
  }

  const int crow = (lane >> 4) * 4;
  #pragma unroll
  for (int i = 0; i < 2; i++){
    #pragma unroll
    for (int j = 0; j < 2; j++){
      int col = n0 + wc*32 + j*16 + l15;
      if (col < N){
        #pragma unroll
        for (int q = 0; q < 4; q++){
          int rowg = m0 + wr*32 + i*16 + crow + q;
          if constexpr (sizeof(CTy) == 4) C[(size_t)rowg*N + col] = acc[i][j][q];
          else                            C[(size_t)rowg*N + col] = (CTy)f2b(acc[i][j][q]);
        }
      }
    }
  }
}

// ---- causal depthwise conv(4) + bias + silu (both dirs) + dt/dA prep ----
__global__ __launch_bounds__(256) void convdt_kernel(const __hip_bfloat16* __restrict__ zx,
    const float* __restrict__ cw, const float* __restrict__ cb,
    const float* __restrict__ dt_bias, const float* __restrict__ A_log,
    __hip_bfloat16* __restrict__ xconv, float* __restrict__ dtb, float* __restrict__ dab)
{
  const int tt = blockIdx.x, b = blockIdx.y, dir = blockIdx.z;
  const int c8 = threadIdx.x * 8;
  if (c8 < CONVDIM){
    size_t rowoff[4]; bool ok[4];
    #pragma unroll
    for (int k = 0; k < 4; k++){
      int s = tt - 3 + k;
      ok[k] = (s >= 0);
      int ss = ok[k] ? s : 0;
      int phys = dir ? (SEQ-1-ss) : ss;
      rowoff[k] = ((size_t)(b*SEQ + phys))*DINPROJ + DINNER + c8;
    }
    float acc[8];
    {
      float4 cb0 = *(const float4*)(cb + c8);
      float4 cb1 = *(const float4*)(cb + c8 + 4);
      acc[0]=cb0.x; acc[1]=cb0.y; acc[2]=cb0.z; acc[3]=cb0.w;
      acc[4]=cb1.x; acc[5]=cb1.y; acc[6]=cb1.z; acc[7]=cb1.w;
    }
    float wv[8][4];
    #pragma unroll
    for (int j = 0; j < 8; j++){
      float4 w4 = *(const float4*)(cw + (size_t)(c8 + j)*4);
      wv[j][0]=w4.x; wv[j][1]=w4.y; wv[j][2]=w4.z; wv[j][3]=w4.w;
    }
    const ushort* zu = (const ushort*)zx;
    #pragma unroll
    for (int k = 0; k < 4; k++){
      if (ok[k]){
        ushort4 v0 = *(const ushort4*)(zu + rowoff[k]);
        ushort4 v1 = *(const ushort4*)(zu + rowoff[k] + 4);
        acc[0] = fmaf(wv[0][k], u2f(v0.x), acc[0]);
        acc[1] = fmaf(wv[1][k], u2f(v0.y), acc[1]);
        acc[2] = fmaf(wv[2][k], u2f(v0.z), acc[2]);
        acc[3] = fmaf(wv[3][k], u2f(v0.w), acc[3]);
        acc[4] = fmaf(wv[4][k], u2f(v1.x), acc[4]);
        acc[5] = fmaf(wv[5][k], u2f(v1.y), acc[5]);
        acc[6] = fmaf(wv[6][k], u2f(v1.z), acc[6]);
        acc[7] = fmaf(wv[7][k], u2f(v1.w), acc[7]);
      }
    }
    ushort* outr = (ushort*)xconv + ((size_t)((dir*BSZ + b)*SEQ + tt))*CONVDIM + c8;
    ushort o[8];
    #pragma unroll
    for (int j = 0; j < 8; j++){
      float s = acc[j] / (1.f + expf(-acc[j]));   // silu
      o[j] = f2bu(s);
    }
    *(ushort4*)(outr)     = make_ushort4(o[0],o[1],o[2],o[3]);
    *(ushort4*)(outr + 4) = make_ushort4(o[4],o[5],o[6],o[7]);
  }
  if (dir == 0 && threadIdx.x < NHEADS){
    int h = threadIdx.x;
    size_t r = (size_t)b*SEQ + tt;
    float raw = b2f(zx[r*DINPROJ + (DINNER + CONVDIM) + h]) + dt_bias[h];
    float sp  = fmaxf(raw, 0.f) + log1pf(expf(-fabsf(raw)));   // stable softplus
    dtb[r*NHEADS + h] = sp;
    dab[r*NHEADS + h] = expf(-sp * expf(A_log[h]));
  }
}

// ======================= chunked selective scan =======================
#define CT 16

// pass1: local chunk scan, state update only. grid (NC-1, NHEADS, 4)
// T14 async-stage: double-buffered LDS tiles, next tile loaded to regs
// during current tile's compute; 1 barrier per tile.
__global__ __launch_bounds__(256) void scan_pass1(const __hip_bfloat16* __restrict__ xconv,
    const float* __restrict__ dtb, const float* __restrict__ dab,
    float* __restrict__ stateBuf, int CL)
{
  const int c = blockIdx.x, h = blockIdx.y, z = blockIdx.z;
  const int b = z & 1, dir = z >> 1;
  const int tid = threadIdx.x, lane = tid & 63, wave = tid >> 6, nb = wave * 16;
  __shared__ __align__(16) float Bc[2][CT][64], Xc[2][CT][64];
  __shared__ float dAc[2][CT], dtc[2][CT];
  float hreg[16];
  #pragma unroll
  for (int j = 0; j < 16; j++) hreg[j] = 0.f;
  const size_t dirbase = (size_t)z * SEQ;
  const int cstart = c * CL;
  const int ttl = tid >> 4, c4 = (tid & 15) << 2;
  const int nt = CL / CT;

  ushort4 cb_, cx_; float cda = 0.f, cdt = 0.f;
  {
    const ushort* rowp = (const ushort*)xconv + (dirbase + cstart + ttl)*(size_t)CONVDIM;
    cb_ = *(const ushort4*)(rowp + DINNER + c4);
    cx_ = *(const ushort4*)(rowp + h*HEADDIM + c4);
    if (tid < CT){
      int phys = dir ? (SEQ-1 - (cstart + tid)) : (cstart + tid);
      size_t r = (size_t)b*SEQ + phys;
      cda = dab[r*NHEADS + h];
      cdt = dtb[r*NHEADS + h];
    }
  }
  Bc[0][ttl][c4+0]=u2f(cb_.x); Bc[0][ttl][c4+1]=u2f(cb_.y);
  Bc[0][ttl][c4+2]=u2f(cb_.z); Bc[0][ttl][c4+3]=u2f(cb_.w);
  Xc[0][ttl][c4+0]=u2f(cx_.x); Xc[0][ttl][c4+1]=u2f(cx_.y);
  Xc[0][ttl][c4+2]=u2f(cx_.z); Xc[0][ttl][c4+3]=u2f(cx_.w);
  if (tid < CT){ dAc[0][tid]=cda; dtc[0][tid]=cdt; }
  __syncthreads();

  int cur = 0;
  for (int it = 0; it < nt; ++it){
    ushort4 nb_, nx_; float nda = 0.f, ndt = 0.f;
    const bool more = (it+1 < nt);
    if (more){
      int c0n = cstart + (it+1)*CT;
      const ushort* rowp = (const ushort*)xconv + (dirbase + c0n + ttl)*(size_t)CONVDIM;
      nb_ = *(const ushort4*)(rowp + DINNER + c4);
      nx_ = *(const ushort4*)(rowp + h*HEADDIM + c4);
      if (tid < CT){
        int phys = dir ? (SEQ-1 - (c0n + tid)) : (c0n + tid);
        size_t r = (size_t)b*SEQ + phys;
        nda = dab[r*NHEADS + h];
        ndt = dtb[r*NHEADS + h];
      }
    }

    #pragma unroll 4
    for (int tt = 0; tt < CT; tt++){
      float dA = dAc[cur][tt];
      float dtx = dtc[cur][tt] * Xc[cur][tt][lane];
      const float4* Bq = (const float4*)&Bc[cur][tt][nb];
      float4 B0 = Bq[0], B1 = Bq[1], B2 = Bq[2], B3 = Bq[3];
      hreg[ 0]=fmaf(dA,hreg[ 0],dtx*B0.x); hreg[ 1]=fmaf(dA,hreg[ 1],dtx*B0.y);
      hreg[ 2]=fmaf(dA,hreg[ 2],dtx*B0.z); hreg[ 3]=fmaf(dA,hreg[ 3],dtx*B0.w);
      hreg[ 4]=fmaf(dA,hreg[ 4],dtx*B1.x); hreg[ 5]=fmaf(dA,hreg[ 5],dtx*B1.y);
      hreg[ 6]=fmaf(dA,hreg[ 6],dtx*B1.z); hreg[ 7]=fmaf(dA,hreg[ 7],dtx*B1.w);
      hreg[ 8]=fmaf(dA,hreg[ 8],dtx*B2.x); hreg[ 9]=fmaf(dA,hreg[ 9],dtx*B2.y);
      hreg[10]=fmaf(dA,hreg[10],dtx*B2.z); hreg[11]=fmaf(dA,hreg[11],dtx*B2.w);
      hreg[12]=fmaf(dA,hreg[12],dtx*B3.x); hreg[13]=fmaf(dA,hreg[13],dtx*B3.y);
      hreg[14]=fmaf(dA,hreg[14],dtx*B3.z); hreg[15]=fmaf(dA,hreg[15],dtx*B3.w);
    }

    if (more){
      int nxt = cur ^ 1;
      Bc[nxt][ttl][c4+0]=u2f(nb_.x); Bc[nxt][ttl][c4+1]=u2f(nb_.y);
      Bc[nxt][ttl][c4+2]=u2f(nb_.z); Bc[nxt][ttl][c4+3]=u2f(nb_.w);
      Xc[nxt][ttl][c4+0]=u2f(nx_.x); Xc[nxt][ttl][c4+1]=u2f(nx_.y);
      Xc[nxt][ttl][c4+2]=u2f(nx_.z); Xc[nxt][ttl][c4+3]=u2f(nx_.w);
      if (tid < CT){ dAc[nxt][tid]=nda; dtc[nxt][tid]=ndt; }
    }
    __syncthreads();
    cur ^= 1;
  }

  float* sp = stateBuf + (((size_t)c*4 + z)*NHEADS + h)*4096 + (size_t)lane*64 + nb;
  *(float4*)(sp +  0) = make_float4(hreg[ 0],hreg[ 1],hreg[ 2],hreg[ 3]);
  *(float4*)(sp +  4) = make_float4(hreg[ 4],hreg[ 5],hreg[ 6],hreg[ 7]);
  *(float4*)(sp +  8) = make_float4(hreg[ 8],hreg[ 9],hreg[10],hreg[11]);
  *(float4*)(sp + 12) = make_float4(hreg[12],hreg[13],hreg[14],hreg[15]);
}

// fixup: h_init[c] = P_{c-1} h_init[c-1] + L_{c-1}; overwrites state[c] (c>=1).
// grid (NHEADS, 4)
__global__ __launch_bounds__(256) void scan_fixup(const float* __restrict__ dab,
    float* __restrict__ stateBuf, int NC, int CL)
{
  const int h = blockIdx.x, z = blockIdx.y;
  const int b = z & 1, dir = z >> 1;
  const int tid = threadIdx.x;
  __shared__ float sdA[SEQ];
  __shared__ float P[8];
  for (int i = tid; i < SEQ; i += 256){
    int phys = dir ? (SEQ-1-i) : i;
    sdA[i] = dab[((size_t)b*SEQ + phys)*NHEADS + h];
  }
  __syncthreads();
  if (tid < NC){
    float p = 1.f;
    for (int i = 0; i < CL; i++) p *= sdA[tid*CL + i];
    P[tid] = p;
  }
  __syncthreads();

  float hrun[16], Lcur[16];
  #pragma unroll
  for (int j = 0; j < 16; j++) hrun[j] = 0.f;
  {
    const float* s0 = stateBuf + ((size_t)z*NHEADS + h)*4096 + (size_t)tid*16;
    #pragma unroll
    for (int j = 0; j < 16; j++) Lcur[j] = s0[j];
  }
  for (int c = 1; c < NC; c++){
    float Pp = P[c-1];
    float hnew[16];
    #pragma unroll
    for (int j = 0; j < 16; j++) hnew[j] = fmaf(Pp, hrun[j], Lcur[j]);
    float* sc = stateBuf + (((size_t)c*4 + z)*NHEADS + h)*4096 + (size_t)tid*16;
    if (c < NC-1){
      #pragma unroll
      for (int j = 0; j < 16; j++) Lcur[j] = sc[j];   // read L_c before overwrite
    }
    #pragma unroll
    for (int j = 0; j < 16; j++) sc[j] = hnew[j];
    #pragma unroll
    for (int j = 0; j < 16; j++) hrun[j] = hnew[j];
  }
}

// pass2: full scan per chunk from h_init. grid (NC, NHEADS, 4)
// T14 async-stage: double-buffered LDS tiles + epilogue z-gate prefetch.
__global__ __launch_bounds__(256) void scan_pass2(const __hip_bfloat16* __restrict__ xconv,
    const __hip_bfloat16* __restrict__ zx, const float* __restrict__ dtb,
    const float* __restrict__ dab, const float* __restrict__ Dp,
    const float* __restrict__ stateBuf, __hip_bfloat16* __restrict__ yg, int CL)
{
  const int c = blockIdx.x, h = blockIdx.y, z = blockIdx.z;
  const int b = z & 1, dir = z >> 1;
  const int tid = threadIdx.x, lane = tid & 63, wave = tid >> 6, nb = wave * 16;
  __shared__ __align__(16) float Bc[2][CT][64], Cc[2][CT][64], Xc[2][CT][64];
  __shared__ __align__(16) float Yp[4][CT][64];
  __shared__ float dAc[2][CT], dtc[2][CT];
  float hreg[16];
  if (c == 0){
    #pragma unroll
    for (int j = 0; j < 16; j++) hreg[j] = 0.f;
  } else {
    const float* sp = stateBuf + (((size_t)c*4 + z)*NHEADS + h)*4096 + (size_t)lane*64 + nb;
    float4 s0 = *(const float4*)(sp+0), s1 = *(const float4*)(sp+4);
    float4 s2 = *(const float4*)(sp+8), s3 = *(const float4*)(sp+12);
    hreg[ 0]=s0.x; hreg[ 1]=s0.y; hreg[ 2]=s0.z; hreg[ 3]=s0.w;
    hreg[ 4]=s1.x; hreg[ 5]=s1.y; hreg[ 6]=s1.z; hreg[ 7]=s1.w;
    hreg[ 8]=s2.x; hreg[ 9]=s2.y; hreg[10]=s2.z; hreg[11]=s2.w;
    hreg[12]=s3.x; hreg[13]=s3.y; hreg[14]=s3.z; hreg[15]=s3.w;
  }
  const float Dh = Dp[h];
  const size_t dirbase = (size_t)z * SEQ;
  const int cstart = c * CL;
  const int ttl = tid >> 4, c4 = (tid & 15) << 2;
  const int nt = CL / CT;

  ushort4 cb_, cc_, cx_, cz_; float cda = 0.f, cdt = 0.f;
  {
    const ushort* rowp = (const ushort*)xconv + (dirbase + cstart + ttl)*(size_t)CONVDIM;
    cb_ = *(const ushort4*)(rowp + DINNER + c4);
    cc_ = *(const ushort4*)(rowp + DINNER + DSTATE + c4);
    cx_ = *(const ushort4*)(rowp + h*HEADDIM + c4);
    int physz = dir ? (SEQ-1 - (cstart + ttl)) : (cstart + ttl);
    size_t rz = (size_t)b*SEQ + physz;
    cz_ = *(const ushort4*)((const ushort*)zx + rz*DINPROJ + h*HEADDIM + c4);
    if (tid < CT){
      int phys = dir ? (SEQ-1 - (cstart + tid)) : (cstart + tid);
      size_t r = (size_t)b*SEQ + phys;
      cda = dab[r*NHEADS + h];
      cdt = dtb[r*NHEADS + h];
    }
  }
  Bc[0][ttl][c4+0]=u2f(cb_.x); Bc[0][ttl][c4+1]=u2f(cb_.y);
  Bc[0][ttl][c4+2]=u2f(cb_.z); Bc[0][ttl][c4+3]=u2f(cb_.w);
  Cc[0][ttl][c4+0]=u2f(cc_.x); Cc[0][ttl][c4+1]=u2f(cc_.y);
  Cc[0][ttl][c4+2]=u2f(cc_.z); Cc[0][ttl][c4+3]=u2f(cc_.w);
  Xc[0][ttl][c4+0]=u2f(cx_.x); Xc[0][ttl][c4+1]=u2f(cx_.y);
  Xc[0][ttl][c4+2]=u2f(cx_.z); Xc[0][ttl][c4+3]=u2f(cx_.w);
  if (tid < CT){ dAc[0][tid]=cda; dtc[0][tid]=cdt; }
  __syncthreads();

  int cur = 0;
  for (int it = 0; it < nt; ++it){
    ushort4 nb_, nc_, nx_, nz_; float nda = 0.f, ndt = 0.f;
    const bool more = (it+1 < nt);
    if (more){
      int c0n = cstart + (it+1)*CT;
      const ushort* rowp = (const ushort*)xconv + (dirbase + c0n + ttl)*(size_t)CONVDIM;
      nb_ = *(const ushort4*)(rowp + DINNER + c4);
      nc_ = *(const ushort4*)(rowp + DINNER + DSTATE + c4);
      nx_ = *(const ushort4*)(rowp + h*HEADDIM + c4);
      int physz = dir ? (SEQ-1 - (c0n + ttl)) : (c0n + ttl);
      size_t rz = (size_t)b*SEQ + physz;
      nz_ = *(const ushort4*)((const ushort*)zx + rz*DINPROJ + h*HEADDIM + c4);
      if (tid < CT){
        int phys = dir ? (SEQ-1 - (c0n + tid)) : (c0n + tid);
        size_t r = (size_t)b*SEQ + phys;
        nda = dab[r*NHEADS + h];
        ndt = dtb[r*NHEADS + h];
      }
    }

    #pragma unroll 4
    for (int tt = 0; tt < CT; tt++){
      float dA = dAc[cur][tt];
      float dtx = dtc[cur][tt] * Xc[cur][tt][lane];
      const float4* Bq = (const float4*)&Bc[cur][tt][nb];
      const float4* Cq = (const float4*)&Cc[cur][tt][nb];
      float4 B0 = Bq[0], B1 = Bq[1], B2 = Bq[2], B3 = Bq[3];
      float4 C0 = Cq[0], C1 = Cq[1], C2 = Cq[2], C3 = Cq[3];
      float y0 = 0.f, y1 = 0.f, y2 = 0.f, y3 = 0.f;
      hreg[ 0]=fmaf(dA,hreg[ 0],dtx*B0.x); y0=fmaf(hreg[ 0],C0.x,y0);
      hreg[ 1]=fmaf(dA,hreg[ 1],dtx*B0.y); y1=fmaf(hreg[ 1],C0.y,y1);
      hreg[ 2]=fmaf(dA,hreg[ 2],dtx*B0.z); y2=fmaf(hreg[ 2],C0.z,y2);
      hreg[ 3]=fmaf(dA,hreg[ 3],dtx*B0.w); y3=fmaf(hreg[ 3],C0.w,y3);
      hreg[ 4]=fmaf(dA,hreg[ 4],dtx*B1.x); y0=fmaf(hreg[ 4],C1.x,y0);
      hreg[ 5]=fmaf(dA,hreg[ 5],dtx*B1.y); y1=fmaf(hreg[ 5],C1.y,y1);
      hreg[ 6]=fmaf(dA,hreg[ 6],dtx*B1.z); y2=fmaf(hreg[ 6],C1.z,y2);
      hreg[ 7]=fmaf(dA,hreg[ 7],dtx*B1.w); y3=fmaf(hreg[ 7],C1.w,y3);
      hreg[ 8]=fmaf(dA,hreg[ 8],dtx*B2.x); y0=fmaf(hreg[ 8],C2.x,y0);
      hreg[ 9]=fmaf(dA,hreg[ 9],dtx*B2.y); y1=fmaf(hreg[ 9],C2.y,y1);
      hreg[10]=fmaf(dA,hreg[10],dtx*B2.z); y2=fmaf(hreg[10],C2.z,y2);
      hreg[11]=fmaf(dA,hreg[11],dtx*B2.w); y3=fmaf(hreg[11],C2.w,y3);
      hreg[12]=fmaf(dA,hreg[12],dtx*B3.x); y0=fmaf(hreg[12],C3.x,y0);
      hreg[13]=fmaf(dA,hreg[13],dtx*B3.y); y1=fmaf(hreg[13],C3.y,y1);
      hreg[14]=fmaf(dA,hreg[14],dtx*B3.z); y2=fmaf(hreg[14],C3.z,y2);
      hreg[15]=fmaf(dA,hreg[15],dtx*B3.w); y3=fmaf(hreg[15],C3.w,y3);
      Yp[wave][tt][lane] = (y0+y1) + (y2+y3);
    }
    __syncthreads();   // Yp ready; all reads of LDS[cur] complete

    if (more){
      int nxt = cur ^ 1;
      Bc[nxt][ttl][c4+0]=u2f(nb_.x); Bc[nxt][ttl][c4+1]=u2f(nb_.y);
      Bc[nxt][ttl][c4+2]=u2f(nb_.z); Bc[nxt][ttl][c4+3]=u2f(nb_.w);
      Cc[nxt][ttl][c4+0]=u2f(nc_.x); Cc[nxt][ttl][c4+1]=u2f(nc_.y);
      Cc[nxt][ttl][c4+2]=u2f(nc_.z); Cc[nxt][ttl][c4+3]=u2f(nc_.w);
      Xc[nxt][ttl][c4+0]=u2f(nx_.x); Xc[nxt][ttl][c4+1]=u2f(nx_.y);
      Xc[nxt][ttl][c4+2]=u2f(nx_.z); Xc[nxt][ttl][c4+3]=u2f(nx_.w);
      if (tid < CT){ dAc[nxt][tid]=nda; dtc[nxt][tid]=ndt; }
    }

    {
      // vectorized epilogue: 4 consecutive p per thread; z prefetched (cz_)
      int tl = ttl, p4 = c4;
      float4 ya  = *(const float4*)&Yp[0][tl][p4];
      float4 yb4 = *(const float4*)&Yp[1][tl][p4];
      float4 yc  = *(const float4*)&Yp[2][tl][p4];
      float4 yd  = *(const float4*)&Yp[3][tl][p4];
      float4 xv  = *(const float4*)&Xc[cur][tl][p4];
      int phys = dir ? (SEQ-1 - (cstart + it*CT + tl)) : (cstart + it*CT + tl);
      size_t r = (size_t)b*SEQ + phys;
      float zf[4] = { u2f(cz_.x), u2f(cz_.y), u2f(cz_.z), u2f(cz_.w) };
      float yv[4] = { ya.x+yb4.x+yc.x+yd.x + Dh*xv.x,
                      ya.y+yb4.y+yc.y+yd.y + Dh*xv.y,
                      ya.z+yb4.z+yc.z+yd.z + Dh*xv.z,
                      ya.w+yb4.w+yc.w+yd.w + Dh*xv.w };
      ushort o[4];
      #pragma unroll
      for (int j = 0; j < 4; j++){
        float sil = zf[j] / (1.f + expf(-zf[j]));
        o[j] = f2bu(yv[j] * sil);
      }
      ushort* op = (ushort*)yg + ((size_t)dir*ROWS + r)*DINNER + h*HEADDIM + p4;
      *(ushort4*)op = make_ushort4(o[0],o[1],o[2],o[3]);
    }
    __syncthreads();   // Yp free for next iter; LDS[cur^1] writes visible
    if (more) cz_ = nz_;
    cur ^= 1;
  }
}

// ---- per-row gated RMSNorm both dirs + combine (fp32 norm_w) -> u bf16 ----
__global__ __launch_bounds__(256) void rmscomb_kernel(const __hip_bfloat16* __restrict__ yg,
    const float* __restrict__ nw, __hip_bfloat16* __restrict__ u)
{
  __shared__ float sh[4];
  const int row = blockIdx.x;
  const __hip_bfloat16* yf = yg + (size_t)row*DINNER;
  const __hip_bfloat16* yb = yg + (size_t)(ROWS + row)*DINNER;
  float vf[6], vb[6]; float sf = 0.f, sb = 0.f;
  #pragma unroll
  for (int i = 0; i < 6; i++){
    int c = threadIdx.x + i*256;
    vf[i] = b2f(yf[c]); sf += vf[i]*vf[i];
    vb[i] = b2f(yb[c]); sb += vb[i]*vb[i];
  }
  sf = block_sum256(sf, sh);
  sb = block_sum256(sb, sh);
  float rf = rsqrtf(sf*(1.f/DINNER) + EPSF);
  float rb = rsqrtf(sb*(1.f/DINNER) + EPSF);
  #pragma unroll
  for (int i = 0; i < 6; i++){
    int c = threadIdx.x + i*256;
    u[(size_t)row*DINNER + c] = f2b((vf[i]*rf + vb[i]*rb) * nw[c]);
  }
}

// ---- ln2 on NP fp32 partials -> bf16 mb ----
template<int NP>
__global__ __launch_bounds__(256) void ln2_kernel(const float* __restrict__ in,
    size_t pstride, const float* __restrict__ w, const float* __restrict__ b,
    __hip_bfloat16* __restrict__ out)
{
  __shared__ float sh[4];
  const int row = blockIdx.x;
  float v[3]; float s = 0.f;
  #pragma unroll
  for (int i = 0; i < 3; i++){
    int c = threadIdx.x + i*256;
    size_t idx = (size_t)row*DMODEL + c;
    float t = 0.f;
    #pragma unroll
    for (int p = 0; p < NP; p++) t += in[p*pstride + idx];
    v[i] = t; s += t;
  }
  s = block_sum256(s, sh);
  float mu = s * (1.f/DMODEL);
  float s2 = 0.f;
  #pragma unroll
  for (int i = 0; i < 3; i++){ float d = v[i]-mu; s2 += d*d; }
  s2 = block_sum256(s2, sh);
  float rs = rsqrtf(s2*(1.f/DMODEL) + EPSF);
  #pragma unroll
  for (int i = 0; i < 3; i++){
    int c = threadIdx.x + i*256;
    out[(size_t)row*DMODEL + c] = f2b((v[i]-mu)*rs*w[c] + b[c]);
  }
}

// ---- exact GELU with fp32 bias (fallback path only) ----
__global__ __launch_bounds__(256) void gelu_kernel(const __hip_bfloat16* __restrict__ g,
    const float* __restrict__ b1, __hip_bfloat16* __restrict__ out)
{
  size_t idx = (size_t)blockIdx.x*256 + threadIdx.x;
  int c = (int)(idx % DFF);
  float v = b2f(g[idx]) + b1[c];
  out[idx] = f2b(0.5f * v * (1.f + erff(v * 0.70710678118654752f)));
}

// ---- final: sum NP fp32 partials + bias + residual -> fp32 out (x4 vec) ----
template<int NP>
__global__ __launch_bounds__(256) void final_kernel(const float* __restrict__ f,
    size_t pstride, const float* __restrict__ bias, const float* __restrict__ x,
    float* __restrict__ out)
{
  size_t i4 = ((size_t)blockIdx.x*256 + threadIdx.x) << 2;
  int c = (int)(i4 % DMODEL);
  float4 bv = *(const float4*)(bias + c);
  float4 xv = *(const float4*)(x + i4);
  float4 s = make_float4(bv.x+xv.x, bv.y+xv.y, bv.z+xv.z, bv.w+xv.w);
  #pragma unroll
  for (int p = 0; p < NP; p++){
    float4 fv = *(const float4*)(f + p*pstride + i4);
    s.x += fv.x; s.y += fv.y; s.z += fv.z; s.w += fv.w;
  }
  *(float4*)(out + i4) = s;
}

extern "C" void kernel_launch(void* const* d_in, const int* in_sizes, int n_in,
                              void* d_out, int out_size, void* d_ws, size_t ws_size,
                              hipStream_t stream)
{
  float* out = (float*)d_out;

  const size_t NEED = 19906560;   // base plan (proven to fit)
  if (ws_size < NEED || n_in < 17){
    zerof_kernel<<<(out_size + 255)/256, 256, 0, stream>>>(out, out_size);
    return;
  }

  const float* x       = (const float*)d_in[0];
  const float* in_proj_w = (const float*)d_in[1];
  const float* conv_w  = (const float*)d_in[2];
  const float* conv_b  = (const float*)d_in[3];
  const float* dt_bias = (const float*)d_in[4];
  const float* A_log   = (const float*)d_in[5];
  const float* D_param = (const float*)d_in[6];
  const float* norm_w  = (const float*)d_in[7];
  const float* out_proj_w = (const float*)d_in[8];
  const float* ln1_w   = (const float*)d_in[9];
  const float* ln1_b   = (const float*)d_in[10];
  const float* ln2_w   = (const float*)d_in[11];
  const float* ln2_b   = (const float*)d_in[12];
  const float* ff_w1   = (const float*)d_in[13];
  const float* ff_b1   = (const float*)d_in[14];
  const float* ff_w2   = (const float*)d_in[15];
  const float* ff_b2   = (const float*)d_in[16];

  char* ws = (char*)d_ws;
  __hip_bfloat16* zx  = (__hip_bfloat16*)(ws + 0);         // 6,602,752
  __hip_bfloat16* xn  = (__hip_bfloat16*)(ws + 6602752);   // 1,572,864 (dead after s2)
  float*          dtb = (float*)(ws + 6602752);            //    98,304 (over xn)
  float*          dab = (float*)(ws + 6701056);            //    98,304
  __hip_bfloat16* xcv = (__hip_bfloat16*)(ws + 6799360);   // 6,815,744 -> 13,615,104
  __hip_bfloat16* yg  = (__hip_bfloat16*)(ws + 13615104);  // 6,291,456 -> 19,906,560
  __hip_bfloat16* u   = (__hip_bfloat16*)(ws + 0);         // over zx (dead after scan)
  float*          mo  = (float*)(ws + 3145728);            // over zx (fallback)
  __hip_bfloat16* mb  = (__hip_bfloat16*)(ws + 0);         // over u (dead)
  __hip_bfloat16* g   = (__hip_bfloat16*)(ws + 6799360);   // over xcv (fallback)
  __hip_bfloat16* gb  = (__hip_bfloat16*)(ws + 13615104);  // over yg (dead)
  float*          fo  = (float*)(ws + 0);                  // over mb (fallback)

  // fast-path extra regions beyond base plan (ws observed ~268 MB):
  const size_t WBALL = 16748544;        // all 4 weight matrices bf16
  const size_t PARTS = 12582912;        // 4 fp32 partials of ROWS*DMODEL
  const size_t CHB   = 1572864;         // per-chunk scan states
  const size_t PSTRIDE = (size_t)ROWS * DMODEL;
  const int WN_IN  = DINPROJ*DMODEL;    // 2,476,032
  const int WN_OUT = DMODEL*DINNER;     // 1,179,648
  const int WN_F1  = DFF*DMODEL;        // 2,359,296
  const int WN_F2  = DMODEL*DFF;        // 2,359,296

  size_t rem = ws_size - NEED;
  bool fast = (rem >= WBALL + PARTS);
  ushort* wb    = (ushort*)(ws + NEED);
  float*  parts = (float*) (ws + NEED + WBALL);
  size_t scanoff = NEED + (fast ? (WBALL + PARTS) : 0);
  size_t srem = ws_size - scanoff;
  int NC = 1;
  if      (srem >= 8*CHB) NC = 8;
  else if (srem >= 4*CHB) NC = 4;
  else if (srem >= 2*CHB) NC = 2;
  float* stateBuf = (float*)(ws + scanoff);
  const int CL = SEQ / NC;

  if (fast){
    // 1+2) fused: weight conversion (all 4) + ln1
    const int wblocks = (WN_IN + WN_OUT + WN_F1 + WN_F2) / 4 / 256;   // 8178 exact
    prep_kernel<<<wblocks + ROWS, 256, 0, stream>>>(in_proj_w, out_proj_w, ff_w1, ff_w2,
        wb, WN_IN, WN_OUT, WN_F1, WN_F2, wblocks, x, ln1_w, ln1_b, xn);
    // 3) in_proj -> zx bf16
    gemm_bb64<__hip_bfloat16,1,0><<<dim3((DINPROJ+63)/64, ROWS/64), 256, 0, stream>>>(
        xn, (const __hip_bfloat16*)wb, zx, nullptr, ROWS, DINPROJ, DMODEL);
  } else {
    ln_kernel<<<ROWS, 256, 0, stream>>>(x, ln1_w, ln1_b, xn);
    gemm_mfma<<<dim3((DINPROJ+63)/64, ROWS/64), 256, 0, stream>>>(xn, in_proj_w, zx, ROWS, DINPROJ, DMODEL);
  }
  // 4) conv + silu + dt/dA
  convdt_kernel<<<dim3(SEQ, BSZ, 2), 256, 0, stream>>>(zx, conv_w, conv_b, dt_bias, A_log, xcv, dtb, dab);
  // 5) chunked scan (separate tiny fixup kernel; pass2 reads one state)
  if (NC > 1){
    scan_pass1<<<dim3(NC-1, NHEADS, 4), 256, 0, stream>>>(xcv, dtb, dab, stateBuf, CL);
    scan_fixup<<<dim3(NHEADS, 4), 256, 0, stream>>>(dab, stateBuf, NC, CL);
  }
  scan_pass2<<<dim3(NC, NHEADS, 4), 256, 0, stream>>>(xcv, zx, dtb, dab, D_param, stateBuf, yg, CL);
  // 6) per-dir RMS + combine -> u
  rmscomb_kernel<<<ROWS, 256, 0, stream>>>(yg, norm_w, u);
  // 7) out_proj [split-K=2, partials] ; 8) ln2 sums partials
  if (fast){
    gemm_bb64<float,2,0><<<dim3(DMODEL/64, ROWS/64, 2), 256, 0, stream>>>(
        u, (const __hip_bfloat16*)(wb + WN_IN), parts, nullptr, ROWS, DMODEL, DINNER);
    ln2_kernel<2><<<ROWS, 256, 0, stream>>>(parts, PSTRIDE, ln2_w, ln2_b, mb);
  } else {
    gemm_mfma<<<dim3(DMODEL/64, ROWS/64), 256, 0, stream>>>(u, out_proj_w, mo, ROWS, DMODEL, DINNER);
    ln2_kernel<1><<<ROWS, 256, 0, stream>>>(mo, 0, ln2_w, ln2_b, mb);
  }
  // 9) ff1 (+bias+gelu fused) -> gb
  if (fast){
    gemm_bb64<__hip_bfloat16,1,1><<<dim3(DFF/64, ROWS/64), 256, 0, stream>>>(
        mb, (const __hip_bfloat16*)(wb + WN_IN + WN_OUT), gb, ff_b1, ROWS, DFF, DMODEL);
  } else {
    gemm_mfma<<<dim3(DFF/64, ROWS/64), 256, 0, stream>>>(mb, ff_w1, g, ROWS, DFF, DMODEL);
    gelu_kernel<<<(ROWS*DFF)/256, 256, 0, stream>>>(g, ff_b1, gb);
  }
  // 10) ff2 [split-K=4, partials] ; 11) final sums + bias + residual
  if (fast){
    gemm_bb64<float,4,0><<<dim3(DMODEL/64, ROWS/64, 4), 256, 0, stream>>>(
        gb, (const __hip_bfloat16*)(wb + WN_IN + WN_OUT + WN_F1), parts, nullptr, ROWS, DMODEL, DFF);
    final_kernel<4><<<(ROWS*DMODEL/4)/256, 256, 0, stream>>>(parts, PSTRIDE, ff_b2, x, out);
  } else {
    gemm_mfma<<<dim3(DMODEL/64, ROWS/64), 256, 0, stream>>>(gb, ff_w2, fo, ROWS, DMODEL, DFF);
    final_kernel<1><<<(ROWS*DMODEL/4)/256, 256, 0, stream>>>(fo, 0, ff_b2, x, out);
  }
}